// Round 4
// baseline (942.920 us; speedup 1.0000x reference)
//
#include <hip/hip_runtime.h>
#include <hip/hip_bf16.h>
#include <math.h>

#define BB 32
#define CC 128
#define HH 512
#define TT 8192
#define KMAX 512

#define NBIN 2048
#define CANDCAP 4096
#define HOTCAP 32768
#define TILES 2048
#define TLCAP 256
// tau ~= 0.83; floor 0.6 keeps ~17k hist entries/batch (33x over K) -> ~0.5M atomics.
#define HFLOOR 0.6f
#define BW (0.875f / 2048.0f)
#define INVBW (2048.0f / 0.875f)
// bf16-MFMA sal noise: sigma ~2.6e-4, worst-case ~3e-3. Margins:
#define DELTA_C2 6e-3f   // candidate slack vs tau (fp64-verified values)
#define DELTA_C1 1.2e-2f // hot-cell slack: candidate slack + bf16 cellmax noise

// ---- fast-path workspace layout (bytes) ----
#define N_HIST 0              // int[32][2048]   (zeroed)
#define N_SUMEXP 262144       // double[32]      (zeroed)
#define N_CANDCNT 262400      // int[32]         (zeroed)
#define N_TILECNT 262528      // int[2048]       (zeroed)
#define N_ZERO 270720
#define N_TAU 270848
#define N_SELCNT 270976
#define N_CELLMAX 271360      // float[2097152]
#define N_TLIST 8659968       // int[2048*256]
#define N_CANDVAL 10757120    // double[32*4096]
#define N_CANDIDX 11805696    // int[32*4096]
#define N_SELIDX 12329984     // int[32*512]
#define N_SELVAL 12395520     // float[32*512]
#define N_SWB 12461056        // short[512*128]  W in MFMA A-frag order
#define N_XF 12592128         // short[32*64*16384]  X in MFMA B-frag order
#define N_DWT 79700992        // float[512*128]  down_w transposed [h][c]
#define N_NEED 79963136

// ---- slow-path (R3) workspace layout ----
#define O_HIST 0
#define O_SUMEXP 262144
#define O_CANDCNT 262400
#define O_HOTCNT 262528
#define O_ZERO 262656
#define O_TAU 262656
#define O_SELCNT 262784
#define O_CELLMAX 263168
#define O_HOTLIST 8651776
#define O_CANDVAL 8782848
#define O_CANDIDX 9831424
#define O_SELIDX 10355712
#define O_SELVAL 10421248

typedef __attribute__((ext_vector_type(8))) short short8;
typedef __attribute__((ext_vector_type(16))) float f32x16;
typedef __attribute__((address_space(3))) unsigned int lds_u32;
typedef const __attribute__((address_space(1))) unsigned int glb_u32;

// ===== Fragment layouts (derived from the verified R3 LDS kernel) =====
// A-frag (W): lane l=(m=l&31,u=l>>5) of wave w in by-slice holds sw[h=by*128+w*32+m][c=kc*16+u*8 .. +8]
//   swb short index = (by*4+w)*4096 + kc*512 + u*256 + m*8
// B-frag (X): lane l holds x[t=bx*128+nt*32+m][c=kc*16+u*8 .. +8] (bf16)
//   xf short index = (b*64+bx)*16384 + nt*4096 + kc*512 + u*256 + m*8
// Both are lane-contiguous: chunk_base + l*16 bytes -> coalesced dwordx4 loads.

// ---------------- prep_w: sw fp32 -> swb bf16 in A-frag order -----------------------
__global__ void prep_w(const float* __restrict__ sw, short* __restrict__ swb) {
  int i = blockIdx.x * 256 + threadIdx.x;  // 8192 chunks of 8 shorts
  int m = i & 31, u = (i >> 5) & 1, kc = (i >> 6) & 7, w = (i >> 9) & 3, by = i >> 11;
  int h = by * 128 + w * 32 + m;
  int c0 = kc * 16 + u * 8;
  float4 f0 = *(const float4*)(sw + (size_t)h * CC + c0);
  float4 f1 = *(const float4*)(sw + (size_t)h * CC + c0 + 4);
  union { __hip_bfloat162 h2; unsigned u; } p0, p1, p2, p3;
  p0.h2 = __float22bfloat162_rn(make_float2(f0.x, f0.y));
  p1.h2 = __float22bfloat162_rn(make_float2(f0.z, f0.w));
  p2.h2 = __float22bfloat162_rn(make_float2(f1.x, f1.y));
  p3.h2 = __float22bfloat162_rn(make_float2(f1.z, f1.w));
  *(uint4*)(swb + (size_t)i * 8) = make_uint4(p0.u, p1.u, p2.u, p3.u);
}

// ---------------- prep_dwt: dw [c][h] -> dwt [h][c] ---------------------------------
__global__ void prep_dwt(const float* __restrict__ dw, float* __restrict__ dwt) {
  int i = blockIdx.x * 256 + threadIdx.x;  // 65536
  int c = i & 127, h = i >> 7;
  dwt[(size_t)h * CC + c] = dw[(size_t)c * HH + h];
}

// ---------------- prep_xt: x [b][c][t] fp32 -> xf bf16 B-frag order -----------------
// grid (64 t-tiles, 32 b), 256 thr. LDS fp32 tile with 4-dword XOR swizzle:
//   addr(t,c) = t*128 + (((c>>2) ^ (t&31))<<2) + (c&3)
__global__ __launch_bounds__(256) void prep_xt(const float* __restrict__ x,
                                               short* __restrict__ xf) {
  __shared__ float Lt[128 * 128];
  int tid = threadIdx.x;
  int b = blockIdx.y, bx = blockIdx.x, t0g = bx * 128;
  const float* xb = x + (size_t)b * CC * TT;
  {
    int cq = tid >> 5, tq = tid & 31, t0 = tq * 4;
#pragma unroll
    for (int p = 0; p < 4; p++) {
      int c0 = p * 32 + cq * 4;
      float r0[4], r1[4], r2[4], r3[4];
      *(float4*)r0 = *(const float4*)(xb + (size_t)(c0 + 0) * TT + t0g + t0);
      *(float4*)r1 = *(const float4*)(xb + (size_t)(c0 + 1) * TT + t0g + t0);
      *(float4*)r2 = *(const float4*)(xb + (size_t)(c0 + 2) * TT + t0g + t0);
      *(float4*)r3 = *(const float4*)(xb + (size_t)(c0 + 3) * TT + t0g + t0);
#pragma unroll
      for (int j = 0; j < 4; j++) {
        int t = t0 + j;
        int addr = t * 128 + ((((c0 >> 2) ^ (t & 31)) << 2));
        *(float4*)&Lt[addr] = make_float4(r0[j], r1[j], r2[j], r3[j]);
      }
    }
  }
  __syncthreads();
  // output: thread = (nt, m, u); loop kc. t = nt*32+m, c0 = kc*16+u*8
  int u = tid & 1, m = (tid >> 1) & 31, nt = (tid >> 6) & 3;
  int t = nt * 32 + m;
  short* dst = xf + ((size_t)b * 64 + bx) * 16384 + nt * 4096 + u * 256 + m * 8;
#pragma unroll
  for (int kc = 0; kc < 8; kc++) {
    int c0 = kc * 16 + u * 8;
    float4 f0 = *(float4*)&Lt[t * 128 + ((((c0 >> 2) ^ (t & 31)) << 2))];
    float4 f1 = *(float4*)&Lt[t * 128 + (((((c0 + 4) >> 2) ^ (t & 31)) << 2))];
    union { __hip_bfloat162 h2; unsigned u; } p0, p1, p2, p3;
    p0.h2 = __float22bfloat162_rn(make_float2(f0.x, f0.y));
    p1.h2 = __float22bfloat162_rn(make_float2(f0.z, f0.w));
    p2.h2 = __float22bfloat162_rn(make_float2(f1.x, f1.y));
    p3.h2 = __float22bfloat162_rn(make_float2(f1.z, f1.w));
    *(uint4*)(dst + kc * 512) = make_uint4(p0.u, p1.u, p2.u, p3.u);
  }
}

// ---------------- pass_a_lds: LDS-staged bf16 MFMA GEMM + stats ---------------------
// The 32KB B tile (xf slice) is staged ONCE per block via async global_load_lds
// (8 x 16B per thread, all in flight, zero VGPR cost). All 8 A-frags prefetched up
// front. One vmcnt(0) drain at the barrier. LDS layout linear == frag order.
// XCD swizzle: 4 by-sharers of each bx land on one XCD (B stage L2-hits).
__global__ __launch_bounds__(256) void pass_a_lds(const short* __restrict__ xf,
                                                  const short* __restrict__ swb,
                                                  const float* __restrict__ sb,
                                                  float* __restrict__ cellmax,
                                                  int* __restrict__ hist,
                                                  double* __restrict__ sumexp) {
  __shared__ short Xs[16384];  // 32KB: exact linear copy of xf slice (b,bx)
  __shared__ double sered[4];
  int tid = threadIdx.x;
  int w = tid >> 6, lane = tid & 63, m = lane & 31, u = lane >> 5;
  int id = blockIdx.x, b = blockIdx.y;
  int bx = ((id >> 5) << 3) | (id & 7);
  int by = (id >> 3) & 3;

  const short* xsl = xf + ((size_t)b * 64 + bx) * 16384;
  {
    // wave w copies bytes [w*8192, (w+1)*8192): 8 calls x (64 lanes x 16B).
    // Global src is per-lane; LDS dst is wave-uniform base (+ HW lane*16).
    const short* gs = xsl + w * 4096 + lane * 8;
    short* ls = &Xs[w * 4096];
#pragma unroll
    for (int i = 0; i < 8; i++) {
      __builtin_amdgcn_global_load_lds((glb_u32*)(gs + i * 512),
                                       (lds_u32*)(ls + i * 512), 16, 0, 0);
    }
  }

  // A-frags: all 8 kc stages up front (32 VGPR, L2-hot swb), in flight with the glds.
  const short* wb_ = swb + (size_t)(by * 4 + w) * 4096 + u * 256 + m * 8;
  short8 afr[8];
#pragma unroll
  for (int kc = 0; kc < 8; kc++) afr[kc] = *(const short8*)(wb_ + kc * 512);

  __syncthreads();  // drains vmcnt(0): glds + A-frag loads all landed

  f32x16 acc0, acc1, acc2, acc3;
#pragma unroll
  for (int r = 0; r < 16; r++) { acc0[r] = 0.f; acc1[r] = 0.f; acc2[r] = 0.f; acc3[r] = 0.f; }

  const short* xr = &Xs[u * 256 + m * 8];  // + nt*4096 + kc*512
#pragma unroll
  for (int kc = 0; kc < 8; kc++) {
    short8 b0 = *(const short8*)(xr + kc * 512);
    short8 b1 = *(const short8*)(xr + 4096 + kc * 512);
    short8 b2 = *(const short8*)(xr + 8192 + kc * 512);
    short8 b3 = *(const short8*)(xr + 12288 + kc * 512);
    acc0 = __builtin_amdgcn_mfma_f32_32x32x16_bf16(afr[kc], b0, acc0, 0, 0, 0);
    acc1 = __builtin_amdgcn_mfma_f32_32x32x16_bf16(afr[kc], b1, acc1, 0, 0, 0);
    acc2 = __builtin_amdgcn_mfma_f32_32x32x16_bf16(afr[kc], b2, acc2, 0, 0, 0);
    acc3 = __builtin_amdgcn_mfma_f32_32x32x16_bf16(afr[kc], b3, acc3, 0, 0, 0);
  }

  // epilogue: bias + max + exp + hist. C/D: col(t)=lane&31, row(h)=8g+q+4u
  int h0 = by * 128;
  float tmax = -1e30f;
  float se = 0.f;
#define EPI(ACC)                                                              \
  {                                                                           \
    _Pragma("unroll") for (int g = 0; g < 4; g++) {                           \
      float bias4[4];                                                         \
      *(float4*)bias4 = *(const float4*)&sb[h0 + w * 32 + g * 8 + u * 4];     \
      _Pragma("unroll") for (int q = 0; q < 4; q++) {                         \
        float s = ACC[g * 4 + q] + bias4[q];                                  \
        tmax = fmaxf(tmax, s);                                                \
        se += __expf(s);                                                      \
        if (s >= HFLOOR) {                                                    \
          int bin = (int)((s - HFLOOR) * INVBW);                              \
          if (bin > NBIN - 1) bin = NBIN - 1;                                 \
          atomicAdd(&hist[b * NBIN + bin], 1);                                \
        }                                                                     \
      }                                                                       \
    }                                                                         \
  }
  EPI(acc0) EPI(acc1) EPI(acc2) EPI(acc3)
#undef EPI
  int cid = ((b * 4 + by) * 64 + bx) * 256 + tid;
  cellmax[cid] = tmax;
  double sed = (double)se;
#pragma unroll
  for (int mm = 1; mm < 64; mm <<= 1) sed += __shfl_xor(sed, mm);
  if (lane == 0) sered[w] = sed;
  __syncthreads();
  if (tid == 0) atomicAdd(&sumexp[b], sered[0] + sered[1] + sered[2] + sered[3]);
}

// ---------------- pass_b: per-batch threshold tau from histogram (parallel) ---------
__global__ void pass_b(const int* __restrict__ hist, float* __restrict__ tau,
                       const int* __restrict__ kptr) {
  __shared__ int hsh[NBIN];
  __shared__ int ps[256];
  int b = blockIdx.x, tid = threadIdx.x;
  int part = 0;
#pragma unroll
  for (int j = 0; j < 8; j++) {
    int v = hist[b * NBIN + tid * 8 + j];
    hsh[tid * 8 + j] = v;
    part += v;
  }
  ps[tid] = part;
  __syncthreads();
  if (tid == 0) {
    int k = kptr[0];
    if (k < 1) k = 1;
    if (k > KMAX) k = KMAX;
    long cum = 0;
    float tv = HFLOOR;
    for (int i = 255; i >= 0; i--) {
      if (cum + ps[i] >= k) {
        long r = k - cum;
        long c2 = 0;
        for (int j = 7; j >= 0; j--) {
          c2 += hsh[i * 8 + j];
          if (c2 >= r) { tv = HFLOOR + (i * 8 + j) * BW; break; }
        }
        break;
      }
      cum += ps[i];
    }
    tau[b] = tv;
  }
}

// ---------------- pass_c1_fast: compact hot cells into per-(b,bx)-tile lists --------
__global__ void pass_c1_fast(const float* __restrict__ cellmax, const float* __restrict__ tau,
                             int* __restrict__ tilecnt, int* __restrict__ tlist) {
  int i = blockIdx.x * blockDim.x + threadIdx.x;  // i == cid
  float v = cellmax[i];
  int b = i >> 16;
  if (v >= tau[b] - DELTA_C1) {
    int tile = (b << 6) | ((i >> 8) & 63);
    int pos = atomicAdd(&tilecnt[tile], 1);
    if (pos < TLCAP) tlist[tile * TLCAP + pos] = i;
  }
}

// ---------------- pass_c2_fast: tiled fp64 recompute of hot cells -------------------
// R3 rewrite. R2 post-mortem: __launch_bounds__(512,4) capped VGPR at 64 -> the
// 16-float4 double-buffer couldn't stay live -> compiler sank loads to uses ->
// same latency-serialized ~4-6k cyc/cell as R1 (~47k cells, VALUBusy-derived).
// Fix: (512,2) = 256-VGPR budget (LDS 67.5KB limits to 2 blk/CU anyway, occupancy
// unchanged); explicit 2-stage ping-pong at 32-float chunks with STATIC buffer
// names, cross-cell wraparound (issue next chunk -> dot current); 4 indep fp64
// accs; tlist prefetch 1 cell ahead; nt-XOR swizzle (R2's m-based swz was
// wave-uniform = no-op; nt varies per 16-lane group -> real conflict axis).
__global__ __launch_bounds__(512, 2) void pass_c2_fast(
    const float* __restrict__ x, const float* __restrict__ sw,
    const float* __restrict__ sb, const float* __restrict__ tau,
    const int* __restrict__ tilecnt, const int* __restrict__ tlist,
    int* __restrict__ candcnt, double* __restrict__ candval, int* __restrict__ candidx) {
  __shared__ float Xt[128 * 132];
  int tile = blockIdx.x;
  int b = tile >> 6, bx = tile & 63;
  int cnt = tilecnt[tile];
  if (cnt <= 0) return;
  if (cnt > TLCAP) cnt = TLCAP;
  int tid = threadIdx.x;
  {
    // t-major staging: thread loads (c, t4..t4+3) float4, writes 4 scalars.
    // col swizzle: cc = c ^ (((t>>5)&3)<<2)  (t>>5 uniform across t4..t4+3)
    int cq = tid >> 5, tq = tid & 31, t4 = tq * 4;
    int sw4 = ((t4 >> 5) & 3) << 2;
    const float* xb = x + (size_t)b * CC * TT + bx * 128;
#pragma unroll
    for (int p = 0; p < 8; p++) {
      int c = p * 16 + cq;
      float4 v = *(const float4*)(xb + (size_t)c * TT + t4);
      int cc = c ^ sw4;
      Xt[(t4 + 0) * 132 + cc] = v.x;
      Xt[(t4 + 1) * 132 + cc] = v.y;
      Xt[(t4 + 2) * 132 + cc] = v.z;
      Xt[(t4 + 3) * 132 + cc] = v.w;
    }
  }
  __syncthreads();
  int wv = tid >> 6, lane = tid & 63;
  int nt = lane >> 4, r = lane & 15;
  int swz = nt << 2;
  float tmb = tau[b] - DELTA_C2;
  int tbase = tile * TLCAP;
  if (wv >= cnt) return;

#define DEC(CID)                                                        \
  {                                                                     \
    int by_ = ((CID) >> 14) & 3, ta_ = (CID) & 255;                     \
    int w_ = ta_ >> 6, lc_ = ta_ & 63, m_ = lc_ & 31, u_ = lc_ >> 5;    \
    h = by_ * 128 + w_ * 32 + (r >> 2) * 8 + (r & 3) + 4 * u_;          \
    t = bx * 128 + nt * 32 + m_;                                        \
    swp = (const float4*)(sw + (size_t)h * CC);                         \
    xrp = &Xt[(nt * 32 + m_) * 132];                                    \
    sbh = sb[h];                                                        \
  }
#define ISSUE(WB, XB, CH)                                               \
  _Pragma("unroll") for (int j = 0; j < 8; j++) {                       \
    WB[j] = swp[(CH) * 8 + j];                                          \
    XB[j] = *(const float4*)(xrp + (((CH) * 32 + j * 4) ^ swz));        \
  }
#define DOT(WB, XB)                                                     \
  _Pragma("unroll") for (int j = 0; j < 8; j++) {                       \
    a0 = fma((double)XB[j].x, (double)WB[j].x, a0);                     \
    a1 = fma((double)XB[j].y, (double)WB[j].y, a1);                     \
    a2 = fma((double)XB[j].z, (double)WB[j].z, a2);                     \
    a3 = fma((double)XB[j].w, (double)WB[j].w, a3);                     \
  }

  float4 wA[8], xA[8], wB[8], xB[8];
  int h, t;
  const float4* swp;
  const float* xrp;
  float sbh;
  int s = wv;
  int cid = tlist[tbase + s];
  DEC(cid);
  ISSUE(wA, xA, 0);  // cell-0 chunk-0 in flight
  for (; s < cnt; ) {
    int sn = s + 8;
    int cidN = (sn < cnt) ? tlist[tbase + sn] : cid;  // prefetch next cell id
    double a0 = 0.0, a1 = 0.0, a2 = 0.0, a3 = 0.0;
    ISSUE(wB, xB, 1); DOT(wA, xA);
    ISSUE(wA, xA, 2); DOT(wB, xB);
    ISSUE(wB, xB, 3); DOT(wA, xA);
    int hO = h, tO = t;
    float sbO = sbh;
    if (sn < cnt) { cid = cidN; DEC(cid); }
    ISSUE(wA, xA, 0); DOT(wB, xB);  // next cell's chunk-0 under last dot
    double acc = a0 + a1 + a2 + a3 + (double)sbO;
    if (acc >= (double)tmb) {
      int pos = atomicAdd(&candcnt[b], 1);
      if (pos < CANDCAP) {
        candval[b * CANDCAP + pos] = acc;
        candidx[b * CANDCAP + pos] = hO * TT + tO;
      }
    }
    s = sn;
  }
#undef DEC
#undef ISSUE
#undef DOT
}

// ---------------- pass_d: exact top-k among candidates ------------------------------
__global__ void pass_d(const int* __restrict__ candcnt, const double* __restrict__ candval,
                       const int* __restrict__ candidx, const double* __restrict__ sumexp,
                       const int* __restrict__ kptr, int* __restrict__ selidx,
                       float* __restrict__ selval, int* __restrict__ selcnt) {
  __shared__ double sv[CANDCAP];
  __shared__ int si[CANDCAP];
  int b = blockIdx.x;
  int n = candcnt[b];
  if (n > CANDCAP) n = CANDCAP;
  int k = kptr[0];
  if (k < 0) k = 0;
  if (k > KMAX) k = KMAX;
  for (int i = threadIdx.x; i < n; i += blockDim.x) {
    sv[i] = candval[b * CANDCAP + i];
    si[i] = candidx[b * CANDCAP + i];
  }
  __syncthreads();
  double S = sumexp[b];
  for (int i = threadIdx.x; i < n; i += blockDim.x) {
    double vi = sv[i];
    int ii = si[i];
    int rank = 0;
    for (int q = 0; q < n; q++) {
      double vq = sv[q];
      rank += (vq > vi) || (vq == vi && si[q] < ii);
    }
    if (rank < k) {
      selidx[b * KMAX + rank] = ii;
      selval[b * KMAX + rank] = (float)(exp(vi) / S);
    }
  }
  if (threadIdx.x == 0) selcnt[b] = n < k ? n : k;
}

// ---------------- pass_e1: out = down_b broadcast -----------------------------------
__global__ void pass_e1(const float* __restrict__ db, float* __restrict__ out) {
  int row = blockIdx.x;  // b*C + c
  int c = row & (CC - 1);
  float v = db[c];
  float4 v4 = make_float4(v, v, v, v);
  float4* o = (float4*)(out + (size_t)row * TT);
#pragma unroll
  for (int q = 0; q < 8; q++) o[q * 256 + threadIdx.x] = v4;
}

// ---------------- pass_e2_fast: scatter using bf16 xf gather + dwt ------------------
// sig from bf16 x: err ~5e-4 abs; out err ~5e-4*val(5e-7)*dw(0.02) ~ 6e-12 << tol.
__global__ void pass_e2_fast(const short* __restrict__ xf, const float* __restrict__ uw,
                             const float* __restrict__ ub, const float* __restrict__ dwt,
                             const int* __restrict__ selidx, const float* __restrict__ selval,
                             const int* __restrict__ selcnt, float* __restrict__ out) {
  int b = blockIdx.y, j = blockIdx.x;
  if (j >= selcnt[b]) return;
  int idx = selidx[b * KMAX + j];
  float val = selval[b * KMAX + j];
  int h = idx >> 13, t = idx & (TT - 1);
  int bx = t >> 7, tl = t & 127, nt = tl >> 5, m = tl & 31;
  int lane = threadIdx.x;  // 64
  const short* xt = xf + ((size_t)b * 64 + bx) * 16384 + nt * 4096 + m * 8;
  int off = (lane >> 3) * 512 + ((lane >> 2) & 1) * 256 + (lane & 3) * 2;
  __hip_bfloat162 hv = *(const __hip_bfloat162*)(xt + off);
  float2 xv = __bfloat1622float2(hv);
  int c0 = lane * 2;
  float2 wv = *(const float2*)(uw + (size_t)h * CC + c0);
  float p = xv.x * wv.x + xv.y * wv.y;
#pragma unroll
  for (int mm = 1; mm < 64; mm <<= 1) p += __shfl_xor(p, mm);
  float sig = p + ub[h];
  float g = sig * val;
  float2 dv = *(const float2*)(dwt + (size_t)h * CC + c0);
  atomicAdd(&out[((size_t)b * CC + c0) * TT + t], g * dv.x);
  atomicAdd(&out[((size_t)b * CC + c0 + 1) * TT + t], g * dv.y);
}

// ================= slow-path (R3, proven) kernels for small ws ======================
__global__ __launch_bounds__(256) void pass_a_slow(const float* __restrict__ x,
                                                   const float* __restrict__ sw,
                                                   const float* __restrict__ sb,
                                                   float* __restrict__ cellmax,
                                                   int* __restrict__ hist,
                                                   double* __restrict__ sumexp) {
  __shared__ short Ws[128 * 128];
  __shared__ short Xs[128 * 128];
  __shared__ float sbs[128];
  int tid = threadIdx.x;
  int b = blockIdx.z, by = blockIdx.y, bx = blockIdx.x;
  int h0 = by * 128, t0g = bx * 128;
  const float* xb = x + (size_t)b * CC * TT;
  {
    int cq = tid >> 5, tq = tid & 31;
    int t0 = tq * 4;
#pragma unroll
    for (int p = 0; p < 4; p++) {
      int c0 = p * 32 + cq * 4;
      float r0[4], r1[4], r2[4], r3[4];
      *(float4*)r0 = *(const float4*)(xb + (size_t)(c0 + 0) * TT + t0g + t0);
      *(float4*)r1 = *(const float4*)(xb + (size_t)(c0 + 1) * TT + t0g + t0);
      *(float4*)r2 = *(const float4*)(xb + (size_t)(c0 + 2) * TT + t0g + t0);
      *(float4*)r3 = *(const float4*)(xb + (size_t)(c0 + 3) * TT + t0g + t0);
#pragma unroll
      for (int j = 0; j < 4; j++) {
        int t = t0 + j;
        int addr = t * 128 + ((((c0 >> 3) ^ (t & 15)) << 3) | (c0 & 7));
        union { __hip_bfloat162 h; unsigned int u; } a0, a1;
        a0.h = __float22bfloat162_rn(make_float2(r0[j], r1[j]));
        a1.h = __float22bfloat162_rn(make_float2(r2[j], r3[j]));
        *(uint2*)&Xs[addr] = make_uint2(a0.u, a1.u);
      }
    }
  }
  {
    int hh = tid >> 1, c4 = (tid & 1) << 2;
#pragma unroll
    for (int k = 0; k < 16; k++) {
      int c0 = k * 8 + c4;
      float r[4];
      *(float4*)r = *(const float4*)(sw + (size_t)(h0 + hh) * CC + c0);
      int addr = hh * 128 + ((((c0 >> 3) ^ (hh & 15)) << 3) | (c0 & 7));
      union { __hip_bfloat162 h; unsigned int u; } a0, a1;
      a0.h = __float22bfloat162_rn(make_float2(r[0], r[1]));
      a1.h = __float22bfloat162_rn(make_float2(r[2], r[3]));
      *(uint2*)&Ws[addr] = make_uint2(a0.u, a1.u);
    }
  }
  if (tid < 128) sbs[tid] = sb[h0 + tid];
  __syncthreads();
  int w = tid >> 6, lane = tid & 63, m = lane & 31, u = lane >> 5;
  f32x16 acc0, acc1, acc2, acc3;
#pragma unroll
  for (int r = 0; r < 16; r++) { acc0[r] = 0.f; acc1[r] = 0.f; acc2[r] = 0.f; acc3[r] = 0.f; }
  const short* wrow = &Ws[(w * 32 + m) * 128];
  const short* xrow = &Xs[m * 128];
#pragma unroll
  for (int kc = 0; kc < 8; kc++) {
    int pc = ((((kc << 1) | u) ^ (m & 15)) << 3);
    short8 af = *(const short8*)(wrow + pc);
    short8 b0 = *(const short8*)(xrow + 0 * 32 * 128 + pc);
    short8 b1 = *(const short8*)(xrow + 1 * 32 * 128 + pc);
    short8 b2 = *(const short8*)(xrow + 2 * 32 * 128 + pc);
    short8 b3 = *(const short8*)(xrow + 3 * 32 * 128 + pc);
    acc0 = __builtin_amdgcn_mfma_f32_32x32x16_bf16(af, b0, acc0, 0, 0, 0);
    acc1 = __builtin_amdgcn_mfma_f32_32x32x16_bf16(af, b1, acc1, 0, 0, 0);
    acc2 = __builtin_amdgcn_mfma_f32_32x32x16_bf16(af, b2, acc2, 0, 0, 0);
    acc3 = __builtin_amdgcn_mfma_f32_32x32x16_bf16(af, b3, acc3, 0, 0, 0);
  }
  float tmax = -1e30f;
  float se = 0.f;
#define EPI(ACC)                                                              \
  {                                                                           \
    _Pragma("unroll") for (int g = 0; g < 4; g++) {                           \
      float bias4[4];                                                         \
      *(float4*)bias4 = *(float4*)&sbs[w * 32 + g * 8 + u * 4];               \
      _Pragma("unroll") for (int q = 0; q < 4; q++) {                         \
        float s = ACC[g * 4 + q] + bias4[q];                                  \
        tmax = fmaxf(tmax, s);                                                \
        se += __expf(s);                                                      \
        if (s >= HFLOOR) {                                                    \
          int bin = (int)((s - HFLOOR) * INVBW);                              \
          if (bin > NBIN - 1) bin = NBIN - 1;                                 \
          atomicAdd(&hist[b * NBIN + bin], 1);                                \
        }                                                                     \
      }                                                                       \
    }                                                                         \
  }
  EPI(acc0) EPI(acc1) EPI(acc2) EPI(acc3)
#undef EPI
  int cid = ((b * 4 + by) * 64 + bx) * 256 + tid;
  cellmax[cid] = tmax;
  double sed = (double)se;
#pragma unroll
  for (int mm = 1; mm < 64; mm <<= 1) sed += __shfl_xor(sed, mm);
  if ((tid & 63) == 0) atomicAdd(&sumexp[b], sed);
}

__global__ void pass_c1_slow(const float* __restrict__ cellmax, const float* __restrict__ tau,
                             int* __restrict__ hotcnt, int* __restrict__ hotlist) {
  int i = blockIdx.x * blockDim.x + threadIdx.x;
  float v = cellmax[i];
  int b = i >> 16;
  if (v >= tau[b] - DELTA_C1) {
    int pos = atomicAdd(hotcnt, 1);
    if (pos < HOTCAP) hotlist[pos] = i;
  }
}

__global__ void pass_c2_slow(const float* __restrict__ x, const float* __restrict__ sw,
                             const float* __restrict__ sb, const float* __restrict__ tau,
                             const int* __restrict__ hotcnt, const int* __restrict__ hotlist,
                             int* __restrict__ candcnt, double* __restrict__ candval,
                             int* __restrict__ candidx) {
  int j = blockIdx.x;
  int n = hotcnt[0];
  if (n > HOTCAP) n = HOTCAP;
  if (j >= n) return;
  int cid = hotlist[j];
  int b = cid >> 16, by = (cid >> 14) & 3, bx = (cid >> 8) & 63;
  int ta = cid & 255;
  int w = ta >> 6, lane = ta & 63, m = lane & 31, u = lane >> 5;
  int e = threadIdx.x;
  int nt = e >> 4, r = e & 15;
  int h = by * 128 + w * 32 + (r >> 2) * 8 + (r & 3) + 4 * u;
  int t = bx * 128 + nt * 32 + m;
  const float* xb = x + (size_t)b * CC * TT;
  double acc = 0.0;
#pragma unroll 8
  for (int c = 0; c < CC; c++)
    acc += (double)xb[(size_t)c * TT + t] * (double)sw[h * CC + c];
  acc += (double)sb[h];
  float tm = tau[b] - DELTA_C2;
  if (acc >= (double)tm) {
    int pos = atomicAdd(&candcnt[b], 1);
    if (pos < CANDCAP) {
      candval[b * CANDCAP + pos] = acc;
      candidx[b * CANDCAP + pos] = h * TT + t;
    }
  }
}

__global__ void pass_e2_slow(const float* __restrict__ x, const float* __restrict__ uw,
                             const float* __restrict__ ub, const float* __restrict__ dw,
                             const int* __restrict__ selidx, const float* __restrict__ selval,
                             const int* __restrict__ selcnt, float* __restrict__ out) {
  int b = blockIdx.y, j = blockIdx.x;
  if (j >= selcnt[b]) return;
  int idx = selidx[b * KMAX + j];
  float val = selval[b * KMAX + j];
  int h = idx >> 13, t = idx & (TT - 1);
  int c = threadIdx.x;
  const float* xb = x + (size_t)b * CC * TT;
  float p = xb[(size_t)c * TT + t] * uw[h * CC + c] +
            xb[(size_t)(c + 64) * TT + t] * uw[h * CC + c + 64];
#pragma unroll
  for (int m = 1; m < 64; m <<= 1) p += __shfl_xor(p, m);
  float sig = p + ub[h];
  float g = sig * val;
  atomicAdd(&out[((size_t)b * CC + c) * TT + t], g * dw[c * HH + h]);
  atomicAdd(&out[((size_t)b * CC + c + 64) * TT + t], g * dw[(c + 64) * HH + h]);
}

extern "C" void kernel_launch(void* const* d_in, const int* in_sizes, int n_in,
                              void* d_out, int out_size, void* d_ws, size_t ws_size,
                              hipStream_t stream) {
  const float* x = (const float*)d_in[0];
  const float* uw = (const float*)d_in[1];
  const float* ub = (const float*)d_in[2];
  const float* sw = (const float*)d_in[3];
  const float* sb = (const float*)d_in[4];
  const float* dw = (const float*)d_in[5];
  const float* db = (const float*)d_in[6];
  const int* kptr = (const int*)d_in[7];
  float* out = (float*)d_out;
  char* ws = (char*)d_ws;

  if (ws_size >= (size_t)N_NEED) {
    int* hist = (int*)(ws + N_HIST);
    double* sumexp = (double*)(ws + N_SUMEXP);
    int* candcnt = (int*)(ws + N_CANDCNT);
    int* tilecnt = (int*)(ws + N_TILECNT);
    float* tau = (float*)(ws + N_TAU);
    int* selcnt = (int*)(ws + N_SELCNT);
    float* cellmax = (float*)(ws + N_CELLMAX);
    int* tlist = (int*)(ws + N_TLIST);
    double* candval = (double*)(ws + N_CANDVAL);
    int* candidx = (int*)(ws + N_CANDIDX);
    int* selidx = (int*)(ws + N_SELIDX);
    float* selval = (float*)(ws + N_SELVAL);
    short* swb = (short*)(ws + N_SWB);
    short* xf = (short*)(ws + N_XF);
    float* dwt = (float*)(ws + N_DWT);

    (void)hipMemsetAsync(d_ws, 0, N_ZERO, stream);
    prep_w<<<32, 256, 0, stream>>>(sw, swb);
    prep_dwt<<<256, 256, 0, stream>>>(dw, dwt);
    prep_xt<<<dim3(64, 32), 256, 0, stream>>>(x, xf);
    pass_a_lds<<<dim3(256, 32), 256, 0, stream>>>(xf, swb, sb, cellmax, hist, sumexp);
    pass_b<<<32, 256, 0, stream>>>(hist, tau, kptr);
    pass_c1_fast<<<8192, 256, 0, stream>>>(cellmax, tau, tilecnt, tlist);
    pass_c2_fast<<<TILES, 512, 0, stream>>>(x, sw, sb, tau, tilecnt, tlist, candcnt,
                                            candval, candidx);
    pass_d<<<32, 256, 0, stream>>>(candcnt, candval, candidx, sumexp, kptr, selidx,
                                   selval, selcnt);
    pass_e1<<<BB * CC, 256, 0, stream>>>(db, out);
    pass_e2_fast<<<dim3(KMAX, BB), 64, 0, stream>>>(xf, uw, ub, dwt, selidx, selval,
                                                    selcnt, out);
  } else {
    int* hist = (int*)(ws + O_HIST);
    double* sumexp = (double*)(ws + O_SUMEXP);
    int* candcnt = (int*)(ws + O_CANDCNT);
    int* hotcnt = (int*)(ws + O_HOTCNT);
    float* tau = (float*)(ws + O_TAU);
    int* selcnt = (int*)(ws + O_SELCNT);
    float* cellmax = (float*)(ws + O_CELLMAX);
    int* hotlist = (int*)(ws + O_HOTLIST);
    double* candval = (double*)(ws + O_CANDVAL);
    int* candidx = (int*)(ws + O_CANDIDX);
    int* selidx = (int*)(ws + O_SELIDX);
    float* selval = (float*)(ws + O_SELVAL);

    (void)hipMemsetAsync(d_ws, 0, O_ZERO, stream);
    pass_a_slow<<<dim3(64, 4, 32), 256, 0, stream>>>(x, sw, sb, cellmax, hist, sumexp);
    pass_b<<<32, 256, 0, stream>>>(hist, tau, kptr);
    pass_c1_slow<<<8192, 256, 0, stream>>>(cellmax, tau, hotcnt, hotlist);
    pass_c2_slow<<<HOTCAP, 64, 0, stream>>>(x, sw, sb, tau, hotcnt, hotlist, candcnt,
                                            candval, candidx);
    pass_d<<<32, 256, 0, stream>>>(candcnt, candval, candidx, sumexp, kptr, selidx,
                                   selval, selcnt);
    pass_e1<<<BB * CC, 256, 0, stream>>>(db, out);
    pass_e2_slow<<<dim3(KMAX, BB), 64, 0, stream>>>(x, uw, ub, dw, selidx, selval,
                                                    selcnt, out);
  }
}

// Round 5
// 924.703 us; speedup vs baseline: 1.0197x; 1.0197x over previous
//
#include <hip/hip_runtime.h>
#include <hip/hip_bf16.h>
#include <math.h>

#define BB 32
#define CC 128
#define HH 512
#define TT 8192
#define KMAX 512

#define NBIN 2048
#define CANDCAP 4096
#define HOTCAP 32768
#define TILES 2048
#define TLCAP 256
// tau ~= 0.83; floor 0.6 keeps ~17k hist entries/batch (33x over K) -> ~0.5M atomics.
#define HFLOOR 0.6f
#define BW (0.875f / 2048.0f)
#define INVBW (2048.0f / 0.875f)
// bf16-MFMA sal noise: sigma ~2.6e-4, worst-case ~3e-3. Margins:
#define DELTA_C2 6e-3f   // candidate slack vs tau (fp64-verified values)
#define DELTA_C1 1.2e-2f // hot-cell slack: candidate slack + bf16 cellmax noise

// ---- fast-path workspace layout (bytes) ----
#define N_HIST 0              // int[32][2048]   (zeroed)
#define N_SUMEXP 262144       // double[32]      (zeroed)
#define N_CANDCNT 262400      // int[32]         (zeroed)
#define N_TILECNT 262528      // int[2048]       (zeroed)
#define N_ZERO 270720
#define N_TAU 270848
#define N_SELCNT 270976
#define N_CELLMAX 271360      // float[2097152]
#define N_TLIST 8659968       // int[2048*256]
#define N_CANDVAL 10757120    // double[32*4096]
#define N_CANDIDX 11805696    // int[32*4096]
#define N_SELIDX 12329984     // int[32*512]
#define N_SELVAL 12395520     // float[32*512]
#define N_SWB 12461056        // short[512*128]  W in MFMA A-frag order
#define N_XF 12592128         // short[32*64*16384]  X in MFMA B-frag order
#define N_DWT 79700992        // float[512*128]  down_w transposed [h][c]
#define N_NEED 79963136

// ---- slow-path (R3) workspace layout ----
#define O_HIST 0
#define O_SUMEXP 262144
#define O_CANDCNT 262400
#define O_HOTCNT 262528
#define O_ZERO 262656
#define O_TAU 262656
#define O_SELCNT 262784
#define O_CELLMAX 263168
#define O_HOTLIST 8651776
#define O_CANDVAL 8782848
#define O_CANDIDX 9831424
#define O_SELIDX 10355712
#define O_SELVAL 10421248

typedef __attribute__((ext_vector_type(8))) short short8;
typedef __attribute__((ext_vector_type(16))) float f32x16;
typedef __attribute__((address_space(3))) unsigned int lds_u32;
typedef const __attribute__((address_space(1))) unsigned int glb_u32;

// ===== Fragment layouts (derived from the verified R3 LDS kernel) =====
// A-frag (W): lane l=(m=l&31,u=l>>5) of wave w in by-slice holds sw[h=by*128+w*32+m][c=kc*16+u*8 .. +8]
//   swb short index = (by*4+w)*4096 + kc*512 + u*256 + m*8
// B-frag (X): lane l holds x[t=bx*128+nt*32+m][c=kc*16+u*8 .. +8] (bf16)
//   xf short index = (b*64+bx)*16384 + nt*4096 + kc*512 + u*256 + m*8
// Both are lane-contiguous: chunk_base + l*16 bytes -> coalesced dwordx4 loads.

// ---------------- prep_w: sw fp32 -> swb bf16 in A-frag order -----------------------
__global__ void prep_w(const float* __restrict__ sw, short* __restrict__ swb) {
  int i = blockIdx.x * 256 + threadIdx.x;  // 8192 chunks of 8 shorts
  int m = i & 31, u = (i >> 5) & 1, kc = (i >> 6) & 7, w = (i >> 9) & 3, by = i >> 11;
  int h = by * 128 + w * 32 + m;
  int c0 = kc * 16 + u * 8;
  float4 f0 = *(const float4*)(sw + (size_t)h * CC + c0);
  float4 f1 = *(const float4*)(sw + (size_t)h * CC + c0 + 4);
  union { __hip_bfloat162 h2; unsigned u; } p0, p1, p2, p3;
  p0.h2 = __float22bfloat162_rn(make_float2(f0.x, f0.y));
  p1.h2 = __float22bfloat162_rn(make_float2(f0.z, f0.w));
  p2.h2 = __float22bfloat162_rn(make_float2(f1.x, f1.y));
  p3.h2 = __float22bfloat162_rn(make_float2(f1.z, f1.w));
  *(uint4*)(swb + (size_t)i * 8) = make_uint4(p0.u, p1.u, p2.u, p3.u);
}

// ---------------- prep_dwt: dw [c][h] -> dwt [h][c] ---------------------------------
__global__ void prep_dwt(const float* __restrict__ dw, float* __restrict__ dwt) {
  int i = blockIdx.x * 256 + threadIdx.x;  // 65536
  int c = i & 127, h = i >> 7;
  dwt[(size_t)h * CC + c] = dw[(size_t)c * HH + h];
}

// ---------------- prep_xt: x [b][c][t] fp32 -> xf bf16 B-frag order -----------------
// grid (64 t-tiles, 32 b), 256 thr. LDS fp32 tile with 4-dword XOR swizzle:
//   addr(t,c) = t*128 + (((c>>2) ^ (t&31))<<2) + (c&3)
__global__ __launch_bounds__(256) void prep_xt(const float* __restrict__ x,
                                               short* __restrict__ xf) {
  __shared__ float Lt[128 * 128];
  int tid = threadIdx.x;
  int b = blockIdx.y, bx = blockIdx.x, t0g = bx * 128;
  const float* xb = x + (size_t)b * CC * TT;
  {
    int cq = tid >> 5, tq = tid & 31, t0 = tq * 4;
#pragma unroll
    for (int p = 0; p < 4; p++) {
      int c0 = p * 32 + cq * 4;
      float r0[4], r1[4], r2[4], r3[4];
      *(float4*)r0 = *(const float4*)(xb + (size_t)(c0 + 0) * TT + t0g + t0);
      *(float4*)r1 = *(const float4*)(xb + (size_t)(c0 + 1) * TT + t0g + t0);
      *(float4*)r2 = *(const float4*)(xb + (size_t)(c0 + 2) * TT + t0g + t0);
      *(float4*)r3 = *(const float4*)(xb + (size_t)(c0 + 3) * TT + t0g + t0);
#pragma unroll
      for (int j = 0; j < 4; j++) {
        int t = t0 + j;
        int addr = t * 128 + ((((c0 >> 2) ^ (t & 31)) << 2));
        *(float4*)&Lt[addr] = make_float4(r0[j], r1[j], r2[j], r3[j]);
      }
    }
  }
  __syncthreads();
  // output: thread = (nt, m, u); loop kc. t = nt*32+m, c0 = kc*16+u*8
  int u = tid & 1, m = (tid >> 1) & 31, nt = (tid >> 6) & 3;
  int t = nt * 32 + m;
  short* dst = xf + ((size_t)b * 64 + bx) * 16384 + nt * 4096 + u * 256 + m * 8;
#pragma unroll
  for (int kc = 0; kc < 8; kc++) {
    int c0 = kc * 16 + u * 8;
    float4 f0 = *(float4*)&Lt[t * 128 + ((((c0 >> 2) ^ (t & 31)) << 2))];
    float4 f1 = *(float4*)&Lt[t * 128 + (((((c0 + 4) >> 2) ^ (t & 31)) << 2))];
    union { __hip_bfloat162 h2; unsigned u; } p0, p1, p2, p3;
    p0.h2 = __float22bfloat162_rn(make_float2(f0.x, f0.y));
    p1.h2 = __float22bfloat162_rn(make_float2(f0.z, f0.w));
    p2.h2 = __float22bfloat162_rn(make_float2(f1.x, f1.y));
    p3.h2 = __float22bfloat162_rn(make_float2(f1.z, f1.w));
    *(uint4*)(dst + kc * 512) = make_uint4(p0.u, p1.u, p2.u, p3.u);
  }
}

// ---------------- pass_a_lds: LDS-staged bf16 MFMA GEMM + stats ---------------------
// The 32KB B tile (xf slice) is staged ONCE per block via async global_load_lds
// (8 x 16B per thread, all in flight, zero VGPR cost). All 8 A-frags prefetched up
// front. One vmcnt(0) drain at the barrier. LDS layout linear == frag order.
// XCD swizzle: 4 by-sharers of each bx land on one XCD (B stage L2-hits).
__global__ __launch_bounds__(256) void pass_a_lds(const short* __restrict__ xf,
                                                  const short* __restrict__ swb,
                                                  const float* __restrict__ sb,
                                                  float* __restrict__ cellmax,
                                                  int* __restrict__ hist,
                                                  double* __restrict__ sumexp) {
  __shared__ short Xs[16384];  // 32KB: exact linear copy of xf slice (b,bx)
  __shared__ double sered[4];
  int tid = threadIdx.x;
  int w = tid >> 6, lane = tid & 63, m = lane & 31, u = lane >> 5;
  int id = blockIdx.x, b = blockIdx.y;
  int bx = ((id >> 5) << 3) | (id & 7);
  int by = (id >> 3) & 3;

  const short* xsl = xf + ((size_t)b * 64 + bx) * 16384;
  {
    // wave w copies bytes [w*8192, (w+1)*8192): 8 calls x (64 lanes x 16B).
    // Global src is per-lane; LDS dst is wave-uniform base (+ HW lane*16).
    const short* gs = xsl + w * 4096 + lane * 8;
    short* ls = &Xs[w * 4096];
#pragma unroll
    for (int i = 0; i < 8; i++) {
      __builtin_amdgcn_global_load_lds((glb_u32*)(gs + i * 512),
                                       (lds_u32*)(ls + i * 512), 16, 0, 0);
    }
  }

  // A-frags: all 8 kc stages up front (32 VGPR, L2-hot swb), in flight with the glds.
  const short* wb_ = swb + (size_t)(by * 4 + w) * 4096 + u * 256 + m * 8;
  short8 afr[8];
#pragma unroll
  for (int kc = 0; kc < 8; kc++) afr[kc] = *(const short8*)(wb_ + kc * 512);

  __syncthreads();  // drains vmcnt(0): glds + A-frag loads all landed

  f32x16 acc0, acc1, acc2, acc3;
#pragma unroll
  for (int r = 0; r < 16; r++) { acc0[r] = 0.f; acc1[r] = 0.f; acc2[r] = 0.f; acc3[r] = 0.f; }

  const short* xr = &Xs[u * 256 + m * 8];  // + nt*4096 + kc*512
#pragma unroll
  for (int kc = 0; kc < 8; kc++) {
    short8 b0 = *(const short8*)(xr + kc * 512);
    short8 b1 = *(const short8*)(xr + 4096 + kc * 512);
    short8 b2 = *(const short8*)(xr + 8192 + kc * 512);
    short8 b3 = *(const short8*)(xr + 12288 + kc * 512);
    acc0 = __builtin_amdgcn_mfma_f32_32x32x16_bf16(afr[kc], b0, acc0, 0, 0, 0);
    acc1 = __builtin_amdgcn_mfma_f32_32x32x16_bf16(afr[kc], b1, acc1, 0, 0, 0);
    acc2 = __builtin_amdgcn_mfma_f32_32x32x16_bf16(afr[kc], b2, acc2, 0, 0, 0);
    acc3 = __builtin_amdgcn_mfma_f32_32x32x16_bf16(afr[kc], b3, acc3, 0, 0, 0);
  }

  // epilogue: bias + max + exp + hist. C/D: col(t)=lane&31, row(h)=8g+q+4u
  int h0 = by * 128;
  float tmax = -1e30f;
  float se = 0.f;
#define EPI(ACC)                                                              \
  {                                                                           \
    _Pragma("unroll") for (int g = 0; g < 4; g++) {                           \
      float bias4[4];                                                         \
      *(float4*)bias4 = *(const float4*)&sb[h0 + w * 32 + g * 8 + u * 4];     \
      _Pragma("unroll") for (int q = 0; q < 4; q++) {                         \
        float s = ACC[g * 4 + q] + bias4[q];                                  \
        tmax = fmaxf(tmax, s);                                                \
        se += __expf(s);                                                      \
        if (s >= HFLOOR) {                                                    \
          int bin = (int)((s - HFLOOR) * INVBW);                              \
          if (bin > NBIN - 1) bin = NBIN - 1;                                 \
          atomicAdd(&hist[b * NBIN + bin], 1);                                \
        }                                                                     \
      }                                                                       \
    }                                                                         \
  }
  EPI(acc0) EPI(acc1) EPI(acc2) EPI(acc3)
#undef EPI
  int cid = ((b * 4 + by) * 64 + bx) * 256 + tid;
  cellmax[cid] = tmax;
  double sed = (double)se;
#pragma unroll
  for (int mm = 1; mm < 64; mm <<= 1) sed += __shfl_xor(sed, mm);
  if (lane == 0) sered[w] = sed;
  __syncthreads();
  if (tid == 0) atomicAdd(&sumexp[b], sered[0] + sered[1] + sered[2] + sered[3]);
}

// ---------------- pass_b: per-batch threshold tau from histogram (parallel) ---------
__global__ void pass_b(const int* __restrict__ hist, float* __restrict__ tau,
                       const int* __restrict__ kptr) {
  __shared__ int hsh[NBIN];
  __shared__ int ps[256];
  int b = blockIdx.x, tid = threadIdx.x;
  int part = 0;
#pragma unroll
  for (int j = 0; j < 8; j++) {
    int v = hist[b * NBIN + tid * 8 + j];
    hsh[tid * 8 + j] = v;
    part += v;
  }
  ps[tid] = part;
  __syncthreads();
  if (tid == 0) {
    int k = kptr[0];
    if (k < 1) k = 1;
    if (k > KMAX) k = KMAX;
    long cum = 0;
    float tv = HFLOOR;
    for (int i = 255; i >= 0; i--) {
      if (cum + ps[i] >= k) {
        long r = k - cum;
        long c2 = 0;
        for (int j = 7; j >= 0; j--) {
          c2 += hsh[i * 8 + j];
          if (c2 >= r) { tv = HFLOOR + (i * 8 + j) * BW; break; }
        }
        break;
      }
      cum += ps[i];
    }
    tau[b] = tv;
  }
}

// ---------------- pass_c1_fast: compact hot cells into per-(b,bx)-tile lists --------
__global__ void pass_c1_fast(const float* __restrict__ cellmax, const float* __restrict__ tau,
                             int* __restrict__ tilecnt, int* __restrict__ tlist) {
  int i = blockIdx.x * blockDim.x + threadIdx.x;  // i == cid
  float v = cellmax[i];
  int b = i >> 16;
  if (v >= tau[b] - DELTA_C1) {
    int tile = (b << 6) | ((i >> 8) & 63);
    int pos = atomicAdd(&tilecnt[tile], 1);
    if (pos < TLCAP) tlist[tile * TLCAP + pos] = i;
  }
}

// ---------------- pass_c2_fast: tiled fp64 recompute of hot cells -------------------
// R4 rewrite. R1-R3 post-mortems: per-LANE sw-row loads are the invariant killer.
// Each lane read its own 512B row = 32 scattered 16-line VMEM insts/cell; buffering
// it needs 128+ VGPR -> R2 (cap 64) sank loads = serialized; R3 (cap 128) spilled
// (WRITE_SIZE 157MB scratch). Fix: COOPERATIVE staging. Per cell the wave needs only
// 16 distinct rows (8KB, 4-lane redundancy). Wave loads them as 8 fully-coalesced
// 1KB dwordx4 insts into 8 float4/lane (gA/gB double-buffer = 64 VGPR, fits), writes
// to a per-wave private LDS pad Ws (16x33 float4; no barrier needed - same-wave ds
// ordering), dot reads Ws with 4-way-broadcast b128 (2-way bank alias = free) and
// Xt with 16-way broadcast. Next cell's loads issue BEFORE the ~1.3k-cyc fp64 dot,
// hiding L2 latency. launch_bounds(512,1): VGPR cap 256 (R2/R3 lesson: cap=256/N),
// usage ~110, no spill. LDS 67.6K(Xt)+67.6K(Ws) = 135KB -> 1 block/CU.
__global__ __launch_bounds__(512, 1) void pass_c2_fast(
    const float* __restrict__ x, const float* __restrict__ sw,
    const float* __restrict__ sb, const float* __restrict__ tau,
    const int* __restrict__ tilecnt, const int* __restrict__ tlist,
    int* __restrict__ candcnt, double* __restrict__ candval, int* __restrict__ candidx) {
  __shared__ float Xt[128 * 132];      // 67584 B, t-major, col-XOR swizzled
  __shared__ float4 Wsh[8 * 16 * 33];  // 67584 B: per-wave 16 rows x 33 float4
  int tile = blockIdx.x;
  int b = tile >> 6, bx = tile & 63;
  int cnt = tilecnt[tile];
  if (cnt <= 0) return;
  if (cnt > TLCAP) cnt = TLCAP;
  int tid = threadIdx.x;
  {
    // t-major staging (as R3): thread loads (c, t4..t4+3) float4, writes 4 scalars.
    int cq = tid >> 5, tq = tid & 31, t4 = tq * 4;
    int sw4 = ((t4 >> 5) & 3) << 2;
    const float* xb = x + (size_t)b * CC * TT + bx * 128;
#pragma unroll
    for (int p = 0; p < 8; p++) {
      int c = p * 16 + cq;
      float4 v = *(const float4*)(xb + (size_t)c * TT + t4);
      int cc = c ^ sw4;
      Xt[(t4 + 0) * 132 + cc] = v.x;
      Xt[(t4 + 1) * 132 + cc] = v.y;
      Xt[(t4 + 2) * 132 + cc] = v.z;
      Xt[(t4 + 3) * 132 + cc] = v.w;
    }
  }
  __syncthreads();  // last barrier; early wave exits below are safe
  int wv = tid >> 6, lane = tid & 63;
  if (wv >= cnt) return;
  int nt = lane >> 4, r = lane & 15;
  int swz = nt << 2;
  float tmb = tau[b] - DELTA_C2;
  int tbase = tile * TLCAP;
  float4* Ws = &Wsh[wv * 528];
  int hi = lane >> 5, col4 = lane & 31;  // staging lane geometry

#define DEC(CID)                                                         \
  {                                                                      \
    int by_ = ((CID) >> 14) & 3, ta_ = (CID) & 255;                      \
    int w_ = ta_ >> 6, lc_ = ta_ & 63, m_ = lc_ & 31, u_ = lc_ >> 5;     \
    hbase = by_ * 128 + w_ * 32 + 4 * u_;                                \
    h = hbase + (r >> 2) * 8 + (r & 3);                                  \
    t = bx * 128 + nt * 32 + m_;                                         \
    xrp = &Xt[(nt * 32 + m_) * 132];                                     \
    sbh = sb[h];                                                         \
  }
  // iter i: lanes cover rows {2i, 2i+1} (h-contiguous pairs), cols 0..31 -> each
  // inst is 1KB contiguous in sw. Full 16-row set = 8 insts.
#define LOADW(G)                                                         \
  _Pragma("unroll") for (int i = 0; i < 8; i++) {                        \
    int row_ = i * 2 + hi;                                               \
    int h_ = hbase + ((row_ >> 2) << 3) + (row_ & 3);                    \
    G[i] = *(const float4*)(sw + (size_t)h_ * CC + col4 * 4);            \
  }
#define WRITEW(G)                                                        \
  _Pragma("unroll") for (int i = 0; i < 8; i++) {                        \
    Ws[(i * 2 + hi) * 33 + col4] = G[i];                                 \
  }
#define DOTEMIT(XRP, HC, TC, SBC)                                        \
  {                                                                      \
    double a0 = 0.0, a1 = 0.0, a2 = 0.0, a3 = 0.0;                       \
    _Pragma("unroll") for (int j = 0; j < 32; j++) {                     \
      float4 w4 = Ws[r * 33 + j];                                        \
      float4 x4 = *(const float4*)((XRP) + ((j * 4) ^ swz));             \
      a0 = fma((double)x4.x, (double)w4.x, a0);                          \
      a1 = fma((double)x4.y, (double)w4.y, a1);                          \
      a2 = fma((double)x4.z, (double)w4.z, a2);                          \
      a3 = fma((double)x4.w, (double)w4.w, a3);                          \
    }                                                                    \
    double acc = a0 + a1 + a2 + a3 + (double)(SBC);                      \
    if (acc >= (double)tmb) {                                            \
      int pos = atomicAdd(&candcnt[b], 1);                               \
      if (pos < CANDCAP) {                                               \
        candval[b * CANDCAP + pos] = acc;                                \
        candidx[b * CANDCAP + pos] = (HC) * TT + (TC);                   \
      }                                                                  \
    }                                                                    \
  }

  float4 gA[8], gB[8];
  int h, t, hbase;
  const float* xrp;
  float sbh;
  int s = wv;
  int cid = tlist[tbase + s];
  DEC(cid);
  LOADW(gA);
  while (true) {
    // phase A: gA holds current cell's rows
    WRITEW(gA);
    {
      const float* xrpC = xrp; int hC = h, tC = t; float sbC = sbh;
      int sn = s + 8;
      bool more = sn < cnt;
      if (more) { cid = tlist[tbase + sn]; DEC(cid); LOADW(gB); }
      DOTEMIT(xrpC, hC, tC, sbC);
      s = sn;
      if (!more) break;
    }
    // phase B: gB holds current cell's rows
    WRITEW(gB);
    {
      const float* xrpC = xrp; int hC = h, tC = t; float sbC = sbh;
      int sn = s + 8;
      bool more = sn < cnt;
      if (more) { cid = tlist[tbase + sn]; DEC(cid); LOADW(gA); }
      DOTEMIT(xrpC, hC, tC, sbC);
      s = sn;
      if (!more) break;
    }
  }
#undef DEC
#undef LOADW
#undef WRITEW
#undef DOTEMIT
}

// ---------------- pass_d: exact top-k among candidates ------------------------------
__global__ void pass_d(const int* __restrict__ candcnt, const double* __restrict__ candval,
                       const int* __restrict__ candidx, const double* __restrict__ sumexp,
                       const int* __restrict__ kptr, int* __restrict__ selidx,
                       float* __restrict__ selval, int* __restrict__ selcnt) {
  __shared__ double sv[CANDCAP];
  __shared__ int si[CANDCAP];
  int b = blockIdx.x;
  int n = candcnt[b];
  if (n > CANDCAP) n = CANDCAP;
  int k = kptr[0];
  if (k < 0) k = 0;
  if (k > KMAX) k = KMAX;
  for (int i = threadIdx.x; i < n; i += blockDim.x) {
    sv[i] = candval[b * CANDCAP + i];
    si[i] = candidx[b * CANDCAP + i];
  }
  __syncthreads();
  double S = sumexp[b];
  for (int i = threadIdx.x; i < n; i += blockDim.x) {
    double vi = sv[i];
    int ii = si[i];
    int rank = 0;
    for (int q = 0; q < n; q++) {
      double vq = sv[q];
      rank += (vq > vi) || (vq == vi && si[q] < ii);
    }
    if (rank < k) {
      selidx[b * KMAX + rank] = ii;
      selval[b * KMAX + rank] = (float)(exp(vi) / S);
    }
  }
  if (threadIdx.x == 0) selcnt[b] = n < k ? n : k;
}

// ---------------- pass_e1: out = down_b broadcast -----------------------------------
__global__ void pass_e1(const float* __restrict__ db, float* __restrict__ out) {
  int row = blockIdx.x;  // b*C + c
  int c = row & (CC - 1);
  float v = db[c];
  float4 v4 = make_float4(v, v, v, v);
  float4* o = (float4*)(out + (size_t)row * TT);
#pragma unroll
  for (int q = 0; q < 8; q++) o[q * 256 + threadIdx.x] = v4;
}

// ---------------- pass_e2_fast: scatter using bf16 xf gather + dwt ------------------
// sig from bf16 x: err ~5e-4 abs; out err ~5e-4*val(5e-7)*dw(0.02) ~ 6e-12 << tol.
__global__ void pass_e2_fast(const short* __restrict__ xf, const float* __restrict__ uw,
                             const float* __restrict__ ub, const float* __restrict__ dwt,
                             const int* __restrict__ selidx, const float* __restrict__ selval,
                             const int* __restrict__ selcnt, float* __restrict__ out) {
  int b = blockIdx.y, j = blockIdx.x;
  if (j >= selcnt[b]) return;
  int idx = selidx[b * KMAX + j];
  float val = selval[b * KMAX + j];
  int h = idx >> 13, t = idx & (TT - 1);
  int bx = t >> 7, tl = t & 127, nt = tl >> 5, m = tl & 31;
  int lane = threadIdx.x;  // 64
  const short* xt = xf + ((size_t)b * 64 + bx) * 16384 + nt * 4096 + m * 8;
  int off = (lane >> 3) * 512 + ((lane >> 2) & 1) * 256 + (lane & 3) * 2;
  __hip_bfloat162 hv = *(const __hip_bfloat162*)(xt + off);
  float2 xv = __bfloat1622float2(hv);
  int c0 = lane * 2;
  float2 wv = *(const float2*)(uw + (size_t)h * CC + c0);
  float p = xv.x * wv.x + xv.y * wv.y;
#pragma unroll
  for (int mm = 1; mm < 64; mm <<= 1) p += __shfl_xor(p, mm);
  float sig = p + ub[h];
  float g = sig * val;
  float2 dv = *(const float2*)(dwt + (size_t)h * CC + c0);
  atomicAdd(&out[((size_t)b * CC + c0) * TT + t], g * dv.x);
  atomicAdd(&out[((size_t)b * CC + c0 + 1) * TT + t], g * dv.y);
}

// ================= slow-path (R3, proven) kernels for small ws ======================
__global__ __launch_bounds__(256) void pass_a_slow(const float* __restrict__ x,
                                                   const float* __restrict__ sw,
                                                   const float* __restrict__ sb,
                                                   float* __restrict__ cellmax,
                                                   int* __restrict__ hist,
                                                   double* __restrict__ sumexp) {
  __shared__ short Ws[128 * 128];
  __shared__ short Xs[128 * 128];
  __shared__ float sbs[128];
  int tid = threadIdx.x;
  int b = blockIdx.z, by = blockIdx.y, bx = blockIdx.x;
  int h0 = by * 128, t0g = bx * 128;
  const float* xb = x + (size_t)b * CC * TT;
  {
    int cq = tid >> 5, tq = tid & 31;
    int t0 = tq * 4;
#pragma unroll
    for (int p = 0; p < 4; p++) {
      int c0 = p * 32 + cq * 4;
      float r0[4], r1[4], r2[4], r3[4];
      *(float4*)r0 = *(const float4*)(xb + (size_t)(c0 + 0) * TT + t0g + t0);
      *(float4*)r1 = *(const float4*)(xb + (size_t)(c0 + 1) * TT + t0g + t0);
      *(float4*)r2 = *(const float4*)(xb + (size_t)(c0 + 2) * TT + t0g + t0);
      *(float4*)r3 = *(const float4*)(xb + (size_t)(c0 + 3) * TT + t0g + t0);
#pragma unroll
      for (int j = 0; j < 4; j++) {
        int t = t0 + j;
        int addr = t * 128 + ((((c0 >> 3) ^ (t & 15)) << 3) | (c0 & 7));
        union { __hip_bfloat162 h; unsigned int u; } a0, a1;
        a0.h = __float22bfloat162_rn(make_float2(r0[j], r1[j]));
        a1.h = __float22bfloat162_rn(make_float2(r2[j], r3[j]));
        *(uint2*)&Xs[addr] = make_uint2(a0.u, a1.u);
      }
    }
  }
  {
    int hh = tid >> 1, c4 = (tid & 1) << 2;
#pragma unroll
    for (int k = 0; k < 16; k++) {
      int c0 = k * 8 + c4;
      float r[4];
      *(float4*)r = *(const float4*)(sw + (size_t)(h0 + hh) * CC + c0);
      int addr = hh * 128 + ((((c0 >> 3) ^ (hh & 15)) << 3) | (c0 & 7));
      union { __hip_bfloat162 h; unsigned int u; } a0, a1;
      a0.h = __float22bfloat162_rn(make_float2(r[0], r[1]));
      a1.h = __float22bfloat162_rn(make_float2(r[2], r[3]));
      *(uint2*)&Ws[addr] = make_uint2(a0.u, a1.u);
    }
  }
  if (tid < 128) sbs[tid] = sb[h0 + tid];
  __syncthreads();
  int w = tid >> 6, lane = tid & 63, m = lane & 31, u = lane >> 5;
  f32x16 acc0, acc1, acc2, acc3;
#pragma unroll
  for (int r = 0; r < 16; r++) { acc0[r] = 0.f; acc1[r] = 0.f; acc2[r] = 0.f; acc3[r] = 0.f; }
  const short* wrow = &Ws[(w * 32 + m) * 128];
  const short* xrow = &Xs[m * 128];
#pragma unroll
  for (int kc = 0; kc < 8; kc++) {
    int pc = ((((kc << 1) | u) ^ (m & 15)) << 3);
    short8 af = *(const short8*)(wrow + pc);
    short8 b0 = *(const short8*)(xrow + 0 * 32 * 128 + pc);
    short8 b1 = *(const short8*)(xrow + 1 * 32 * 128 + pc);
    short8 b2 = *(const short8*)(xrow + 2 * 32 * 128 + pc);
    short8 b3 = *(const short8*)(xrow + 3 * 32 * 128 + pc);
    acc0 = __builtin_amdgcn_mfma_f32_32x32x16_bf16(af, b0, acc0, 0, 0, 0);
    acc1 = __builtin_amdgcn_mfma_f32_32x32x16_bf16(af, b1, acc1, 0, 0, 0);
    acc2 = __builtin_amdgcn_mfma_f32_32x32x16_bf16(af, b2, acc2, 0, 0, 0);
    acc3 = __builtin_amdgcn_mfma_f32_32x32x16_bf16(af, b3, acc3, 0, 0, 0);
  }
  float tmax = -1e30f;
  float se = 0.f;
#define EPI(ACC)                                                              \
  {                                                                           \
    _Pragma("unroll") for (int g = 0; g < 4; g++) {                           \
      float bias4[4];                                                         \
      *(float4*)bias4 = *(float4*)&sbs[w * 32 + g * 8 + u * 4];               \
      _Pragma("unroll") for (int q = 0; q < 4; q++) {                         \
        float s = ACC[g * 4 + q] + bias4[q];                                  \
        tmax = fmaxf(tmax, s);                                                \
        se += __expf(s);                                                      \
        if (s >= HFLOOR) {                                                    \
          int bin = (int)((s - HFLOOR) * INVBW);                              \
          if (bin > NBIN - 1) bin = NBIN - 1;                                 \
          atomicAdd(&hist[b * NBIN + bin], 1);                                \
        }                                                                     \
      }                                                                       \
    }                                                                         \
  }
  EPI(acc0) EPI(acc1) EPI(acc2) EPI(acc3)
#undef EPI
  int cid = ((b * 4 + by) * 64 + bx) * 256 + tid;
  cellmax[cid] = tmax;
  double sed = (double)se;
#pragma unroll
  for (int mm = 1; mm < 64; mm <<= 1) sed += __shfl_xor(sed, mm);
  if ((tid & 63) == 0) atomicAdd(&sumexp[b], sed);
}

__global__ void pass_c1_slow(const float* __restrict__ cellmax, const float* __restrict__ tau,
                             int* __restrict__ hotcnt, int* __restrict__ hotlist) {
  int i = blockIdx.x * blockDim.x + threadIdx.x;
  float v = cellmax[i];
  int b = i >> 16;
  if (v >= tau[b] - DELTA_C1) {
    int pos = atomicAdd(hotcnt, 1);
    if (pos < HOTCAP) hotlist[pos] = i;
  }
}

__global__ void pass_c2_slow(const float* __restrict__ x, const float* __restrict__ sw,
                             const float* __restrict__ sb, const float* __restrict__ tau,
                             const int* __restrict__ hotcnt, const int* __restrict__ hotlist,
                             int* __restrict__ candcnt, double* __restrict__ candval,
                             int* __restrict__ candidx) {
  int j = blockIdx.x;
  int n = hotcnt[0];
  if (n > HOTCAP) n = HOTCAP;
  if (j >= n) return;
  int cid = hotlist[j];
  int b = cid >> 16, by = (cid >> 14) & 3, bx = (cid >> 8) & 63;
  int ta = cid & 255;
  int w = ta >> 6, lane = ta & 63, m = lane & 31, u = lane >> 5;
  int e = threadIdx.x;
  int nt = e >> 4, r = e & 15;
  int h = by * 128 + w * 32 + (r >> 2) * 8 + (r & 3) + 4 * u;
  int t = bx * 128 + nt * 32 + m;
  const float* xb = x + (size_t)b * CC * TT;
  double acc = 0.0;
#pragma unroll 8
  for (int c = 0; c < CC; c++)
    acc += (double)xb[(size_t)c * TT + t] * (double)sw[h * CC + c];
  acc += (double)sb[h];
  float tm = tau[b] - DELTA_C2;
  if (acc >= (double)tm) {
    int pos = atomicAdd(&candcnt[b], 1);
    if (pos < CANDCAP) {
      candval[b * CANDCAP + pos] = acc;
      candidx[b * CANDCAP + pos] = h * TT + t;
    }
  }
}

__global__ void pass_e2_slow(const float* __restrict__ x, const float* __restrict__ uw,
                             const float* __restrict__ ub, const float* __restrict__ dw,
                             const int* __restrict__ selidx, const float* __restrict__ selval,
                             const int* __restrict__ selcnt, float* __restrict__ out) {
  int b = blockIdx.y, j = blockIdx.x;
  if (j >= selcnt[b]) return;
  int idx = selidx[b * KMAX + j];
  float val = selval[b * KMAX + j];
  int h = idx >> 13, t = idx & (TT - 1);
  int c = threadIdx.x;
  const float* xb = x + (size_t)b * CC * TT;
  float p = xb[(size_t)c * TT + t] * uw[h * CC + c] +
            xb[(size_t)(c + 64) * TT + t] * uw[h * CC + c + 64];
#pragma unroll
  for (int m = 1; m < 64; m <<= 1) p += __shfl_xor(p, m);
  float sig = p + ub[h];
  float g = sig * val;
  atomicAdd(&out[((size_t)b * CC + c) * TT + t], g * dw[c * HH + h]);
  atomicAdd(&out[((size_t)b * CC + c + 64) * TT + t], g * dw[(c + 64) * HH + h]);
}

extern "C" void kernel_launch(void* const* d_in, const int* in_sizes, int n_in,
                              void* d_out, int out_size, void* d_ws, size_t ws_size,
                              hipStream_t stream) {
  const float* x = (const float*)d_in[0];
  const float* uw = (const float*)d_in[1];
  const float* ub = (const float*)d_in[2];
  const float* sw = (const float*)d_in[3];
  const float* sb = (const float*)d_in[4];
  const float* dw = (const float*)d_in[5];
  const float* db = (const float*)d_in[6];
  const int* kptr = (const int*)d_in[7];
  float* out = (float*)d_out;
  char* ws = (char*)d_ws;

  if (ws_size >= (size_t)N_NEED) {
    int* hist = (int*)(ws + N_HIST);
    double* sumexp = (double*)(ws + N_SUMEXP);
    int* candcnt = (int*)(ws + N_CANDCNT);
    int* tilecnt = (int*)(ws + N_TILECNT);
    float* tau = (float*)(ws + N_TAU);
    int* selcnt = (int*)(ws + N_SELCNT);
    float* cellmax = (float*)(ws + N_CELLMAX);
    int* tlist = (int*)(ws + N_TLIST);
    double* candval = (double*)(ws + N_CANDVAL);
    int* candidx = (int*)(ws + N_CANDIDX);
    int* selidx = (int*)(ws + N_SELIDX);
    float* selval = (float*)(ws + N_SELVAL);
    short* swb = (short*)(ws + N_SWB);
    short* xf = (short*)(ws + N_XF);
    float* dwt = (float*)(ws + N_DWT);

    (void)hipMemsetAsync(d_ws, 0, N_ZERO, stream);
    prep_w<<<32, 256, 0, stream>>>(sw, swb);
    prep_dwt<<<256, 256, 0, stream>>>(dw, dwt);
    prep_xt<<<dim3(64, 32), 256, 0, stream>>>(x, xf);
    pass_a_lds<<<dim3(256, 32), 256, 0, stream>>>(xf, swb, sb, cellmax, hist, sumexp);
    pass_b<<<32, 256, 0, stream>>>(hist, tau, kptr);
    pass_c1_fast<<<8192, 256, 0, stream>>>(cellmax, tau, tilecnt, tlist);
    pass_c2_fast<<<TILES, 512, 0, stream>>>(x, sw, sb, tau, tilecnt, tlist, candcnt,
                                            candval, candidx);
    pass_d<<<32, 256, 0, stream>>>(candcnt, candval, candidx, sumexp, kptr, selidx,
                                   selval, selcnt);
    pass_e1<<<BB * CC, 256, 0, stream>>>(db, out);
    pass_e2_fast<<<dim3(KMAX, BB), 64, 0, stream>>>(xf, uw, ub, dwt, selidx, selval,
                                                    selcnt, out);
  } else {
    int* hist = (int*)(ws + O_HIST);
    double* sumexp = (double*)(ws + O_SUMEXP);
    int* candcnt = (int*)(ws + O_CANDCNT);
    int* hotcnt = (int*)(ws + O_HOTCNT);
    float* tau = (float*)(ws + O_TAU);
    int* selcnt = (int*)(ws + O_SELCNT);
    float* cellmax = (float*)(ws + O_CELLMAX);
    int* hotlist = (int*)(ws + O_HOTLIST);
    double* candval = (double*)(ws + O_CANDVAL);
    int* candidx = (int*)(ws + O_CANDIDX);
    int* selidx = (int*)(ws + O_SELIDX);
    float* selval = (float*)(ws + O_SELVAL);

    (void)hipMemsetAsync(d_ws, 0, O_ZERO, stream);
    pass_a_slow<<<dim3(64, 4, 32), 256, 0, stream>>>(x, sw, sb, cellmax, hist, sumexp);
    pass_b<<<32, 256, 0, stream>>>(hist, tau, kptr);
    pass_c1_slow<<<8192, 256, 0, stream>>>(cellmax, tau, hotcnt, hotlist);
    pass_c2_slow<<<HOTCAP, 64, 0, stream>>>(x, sw, sb, tau, hotcnt, hotlist, candcnt,
                                            candval, candidx);
    pass_d<<<32, 256, 0, stream>>>(candcnt, candval, candidx, sumexp, kptr, selidx,
                                   selval, selcnt);
    pass_e1<<<BB * CC, 256, 0, stream>>>(db, out);
    pass_e2_slow<<<dim3(KMAX, BB), 64, 0, stream>>>(x, uw, ub, dw, selidx, selval,
                                                    selcnt, out);
  }
}

// Round 6
// 923.138 us; speedup vs baseline: 1.0214x; 1.0017x over previous
//
#include <hip/hip_runtime.h>
#include <hip/hip_bf16.h>
#include <math.h>

#define BB 32
#define CC 128
#define HH 512
#define TT 8192
#define KMAX 512

#define NBIN 2048
#define CANDCAP 4096
#define HOTCAP 32768
#define TILES 2048
#define TLCAP 256
// tau ~= 0.83; floor 0.6 keeps ~17k hist entries/batch (33x over K) -> ~0.5M atomics.
#define HFLOOR 0.6f
#define BW (0.875f / 2048.0f)
#define INVBW (2048.0f / 0.875f)
// bf16-MFMA sal noise: sigma ~2.6e-4, worst-case ~3e-3. Margins:
#define DELTA_C2 6e-3f   // candidate slack vs tau (fp64-verified values)
#define DELTA_C1 1.2e-2f // hot-cell slack: candidate slack + bf16 cellmax noise

// ---- fast-path workspace layout (bytes) ----
#define N_HIST 0              // int[32][2048]   (zeroed)
#define N_SUMEXP 262144       // double[32]      (zeroed)
#define N_CANDCNT 262400      // int[32]         (zeroed)
#define N_TILECNT 262528      // int[2048]       (zeroed)
#define N_ZERO 270720
#define N_TAU 270848
#define N_SELCNT 270976
#define N_CELLMAX 271360      // float[2097152]
#define N_TLIST 8659968       // int[2048*256]
#define N_CANDVAL 10757120    // double[32*4096]
#define N_CANDIDX 11805696    // int[32*4096]
#define N_SELIDX 12329984     // int[32*512]
#define N_SELVAL 12395520     // float[32*512]
#define N_SWB 12461056        // short[512*128]  W in MFMA A-frag order
#define N_XF 12592128         // short[32*64*16384]  X in MFMA B-frag order
#define N_DWT 79700992        // float[512*128]  down_w transposed [h][c]
#define N_NEED 79963136

// ---- slow-path (R3) workspace layout ----
#define O_HIST 0
#define O_SUMEXP 262144
#define O_CANDCNT 262400
#define O_HOTCNT 262528
#define O_ZERO 262656
#define O_TAU 262656
#define O_SELCNT 262784
#define O_CELLMAX 263168
#define O_HOTLIST 8651776
#define O_CANDVAL 8782848
#define O_CANDIDX 9831424
#define O_SELIDX 10355712
#define O_SELVAL 10421248

typedef __attribute__((ext_vector_type(8))) short short8;
typedef __attribute__((ext_vector_type(16))) float f32x16;
typedef __attribute__((address_space(3))) unsigned int lds_u32;
typedef const __attribute__((address_space(1))) unsigned int glb_u32;

// ===== Fragment layouts (derived from the verified R3 LDS kernel) =====
// A-frag (W): lane l=(m=l&31,u=l>>5) of wave w in by-slice holds sw[h=by*128+w*32+m][c=kc*16+u*8 .. +8]
//   swb short index = (by*4+w)*4096 + kc*512 + u*256 + m*8
// B-frag (X): lane l holds x[t=bx*128+nt*32+m][c=kc*16+u*8 .. +8] (bf16)
//   xf short index = (b*64+bx)*16384 + nt*4096 + kc*512 + u*256 + m*8
// Both are lane-contiguous: chunk_base + l*16 bytes -> coalesced dwordx4 loads.

// ---------------- prep_w: sw fp32 -> swb bf16 in A-frag order -----------------------
__global__ void prep_w(const float* __restrict__ sw, short* __restrict__ swb) {
  int i = blockIdx.x * 256 + threadIdx.x;  // 8192 chunks of 8 shorts
  int m = i & 31, u = (i >> 5) & 1, kc = (i >> 6) & 7, w = (i >> 9) & 3, by = i >> 11;
  int h = by * 128 + w * 32 + m;
  int c0 = kc * 16 + u * 8;
  float4 f0 = *(const float4*)(sw + (size_t)h * CC + c0);
  float4 f1 = *(const float4*)(sw + (size_t)h * CC + c0 + 4);
  union { __hip_bfloat162 h2; unsigned u; } p0, p1, p2, p3;
  p0.h2 = __float22bfloat162_rn(make_float2(f0.x, f0.y));
  p1.h2 = __float22bfloat162_rn(make_float2(f0.z, f0.w));
  p2.h2 = __float22bfloat162_rn(make_float2(f1.x, f1.y));
  p3.h2 = __float22bfloat162_rn(make_float2(f1.z, f1.w));
  *(uint4*)(swb + (size_t)i * 8) = make_uint4(p0.u, p1.u, p2.u, p3.u);
}

// ---------------- prep_dwt: dw [c][h] -> dwt [h][c] ---------------------------------
__global__ void prep_dwt(const float* __restrict__ dw, float* __restrict__ dwt) {
  int i = blockIdx.x * 256 + threadIdx.x;  // 65536
  int c = i & 127, h = i >> 7;
  dwt[(size_t)h * CC + c] = dw[(size_t)c * HH + h];
}

// ---------------- prep_xt: x [b][c][t] fp32 -> xf bf16 B-frag order -----------------
// grid (64 t-tiles, 32 b), 256 thr. LDS fp32 tile with 4-dword XOR swizzle:
//   addr(t,c) = t*128 + (((c>>2) ^ (t&31))<<2) + (c&3)
__global__ __launch_bounds__(256) void prep_xt(const float* __restrict__ x,
                                               short* __restrict__ xf) {
  __shared__ float Lt[128 * 128];
  int tid = threadIdx.x;
  int b = blockIdx.y, bx = blockIdx.x, t0g = bx * 128;
  const float* xb = x + (size_t)b * CC * TT;
  {
    int cq = tid >> 5, tq = tid & 31, t0 = tq * 4;
#pragma unroll
    for (int p = 0; p < 4; p++) {
      int c0 = p * 32 + cq * 4;
      float r0[4], r1[4], r2[4], r3[4];
      *(float4*)r0 = *(const float4*)(xb + (size_t)(c0 + 0) * TT + t0g + t0);
      *(float4*)r1 = *(const float4*)(xb + (size_t)(c0 + 1) * TT + t0g + t0);
      *(float4*)r2 = *(const float4*)(xb + (size_t)(c0 + 2) * TT + t0g + t0);
      *(float4*)r3 = *(const float4*)(xb + (size_t)(c0 + 3) * TT + t0g + t0);
#pragma unroll
      for (int j = 0; j < 4; j++) {
        int t = t0 + j;
        int addr = t * 128 + ((((c0 >> 2) ^ (t & 31)) << 2));
        *(float4*)&Lt[addr] = make_float4(r0[j], r1[j], r2[j], r3[j]);
      }
    }
  }
  __syncthreads();
  // output: thread = (nt, m, u); loop kc. t = nt*32+m, c0 = kc*16+u*8
  int u = tid & 1, m = (tid >> 1) & 31, nt = (tid >> 6) & 3;
  int t = nt * 32 + m;
  short* dst = xf + ((size_t)b * 64 + bx) * 16384 + nt * 4096 + u * 256 + m * 8;
#pragma unroll
  for (int kc = 0; kc < 8; kc++) {
    int c0 = kc * 16 + u * 8;
    float4 f0 = *(float4*)&Lt[t * 128 + ((((c0 >> 2) ^ (t & 31)) << 2))];
    float4 f1 = *(float4*)&Lt[t * 128 + (((((c0 + 4) >> 2) ^ (t & 31)) << 2))];
    union { __hip_bfloat162 h2; unsigned u; } p0, p1, p2, p3;
    p0.h2 = __float22bfloat162_rn(make_float2(f0.x, f0.y));
    p1.h2 = __float22bfloat162_rn(make_float2(f0.z, f0.w));
    p2.h2 = __float22bfloat162_rn(make_float2(f1.x, f1.y));
    p3.h2 = __float22bfloat162_rn(make_float2(f1.z, f1.w));
    *(uint4*)(dst + kc * 512) = make_uint4(p0.u, p1.u, p2.u, p3.u);
  }
}

// ---------------- pass_a_lds: LDS-staged bf16 MFMA GEMM + stats ---------------------
// The 32KB B tile (xf slice) is staged ONCE per block via async global_load_lds
// (8 x 16B per thread, all in flight, zero VGPR cost). All 8 A-frags prefetched up
// front. One vmcnt(0) drain at the barrier. LDS layout linear == frag order.
// XCD swizzle: 4 by-sharers of each bx land on one XCD (B stage L2-hits).
__global__ __launch_bounds__(256) void pass_a_lds(const short* __restrict__ xf,
                                                  const short* __restrict__ swb,
                                                  const float* __restrict__ sb,
                                                  float* __restrict__ cellmax,
                                                  int* __restrict__ hist,
                                                  double* __restrict__ sumexp) {
  __shared__ short Xs[16384];  // 32KB: exact linear copy of xf slice (b,bx)
  __shared__ double sered[4];
  int tid = threadIdx.x;
  int w = tid >> 6, lane = tid & 63, m = lane & 31, u = lane >> 5;
  int id = blockIdx.x, b = blockIdx.y;
  int bx = ((id >> 5) << 3) | (id & 7);
  int by = (id >> 3) & 3;

  const short* xsl = xf + ((size_t)b * 64 + bx) * 16384;
  {
    // wave w copies bytes [w*8192, (w+1)*8192): 8 calls x (64 lanes x 16B).
    // Global src is per-lane; LDS dst is wave-uniform base (+ HW lane*16).
    const short* gs = xsl + w * 4096 + lane * 8;
    short* ls = &Xs[w * 4096];
#pragma unroll
    for (int i = 0; i < 8; i++) {
      __builtin_amdgcn_global_load_lds((glb_u32*)(gs + i * 512),
                                       (lds_u32*)(ls + i * 512), 16, 0, 0);
    }
  }

  // A-frags: all 8 kc stages up front (32 VGPR, L2-hot swb), in flight with the glds.
  const short* wb_ = swb + (size_t)(by * 4 + w) * 4096 + u * 256 + m * 8;
  short8 afr[8];
#pragma unroll
  for (int kc = 0; kc < 8; kc++) afr[kc] = *(const short8*)(wb_ + kc * 512);

  __syncthreads();  // drains vmcnt(0): glds + A-frag loads all landed

  f32x16 acc0, acc1, acc2, acc3;
#pragma unroll
  for (int r = 0; r < 16; r++) { acc0[r] = 0.f; acc1[r] = 0.f; acc2[r] = 0.f; acc3[r] = 0.f; }

  const short* xr = &Xs[u * 256 + m * 8];  // + nt*4096 + kc*512
#pragma unroll
  for (int kc = 0; kc < 8; kc++) {
    short8 b0 = *(const short8*)(xr + kc * 512);
    short8 b1 = *(const short8*)(xr + 4096 + kc * 512);
    short8 b2 = *(const short8*)(xr + 8192 + kc * 512);
    short8 b3 = *(const short8*)(xr + 12288 + kc * 512);
    acc0 = __builtin_amdgcn_mfma_f32_32x32x16_bf16(afr[kc], b0, acc0, 0, 0, 0);
    acc1 = __builtin_amdgcn_mfma_f32_32x32x16_bf16(afr[kc], b1, acc1, 0, 0, 0);
    acc2 = __builtin_amdgcn_mfma_f32_32x32x16_bf16(afr[kc], b2, acc2, 0, 0, 0);
    acc3 = __builtin_amdgcn_mfma_f32_32x32x16_bf16(afr[kc], b3, acc3, 0, 0, 0);
  }

  // epilogue: bias + max + exp + hist. C/D: col(t)=lane&31, row(h)=8g+q+4u
  int h0 = by * 128;
  float tmax = -1e30f;
  float se = 0.f;
#define EPI(ACC)                                                              \
  {                                                                           \
    _Pragma("unroll") for (int g = 0; g < 4; g++) {                           \
      float bias4[4];                                                         \
      *(float4*)bias4 = *(const float4*)&sb[h0 + w * 32 + g * 8 + u * 4];     \
      _Pragma("unroll") for (int q = 0; q < 4; q++) {                         \
        float s = ACC[g * 4 + q] + bias4[q];                                  \
        tmax = fmaxf(tmax, s);                                                \
        se += __expf(s);                                                      \
        if (s >= HFLOOR) {                                                    \
          int bin = (int)((s - HFLOOR) * INVBW);                              \
          if (bin > NBIN - 1) bin = NBIN - 1;                                 \
          atomicAdd(&hist[b * NBIN + bin], 1);                                \
        }                                                                     \
      }                                                                       \
    }                                                                         \
  }
  EPI(acc0) EPI(acc1) EPI(acc2) EPI(acc3)
#undef EPI
  int cid = ((b * 4 + by) * 64 + bx) * 256 + tid;
  cellmax[cid] = tmax;
  double sed = (double)se;
#pragma unroll
  for (int mm = 1; mm < 64; mm <<= 1) sed += __shfl_xor(sed, mm);
  if (lane == 0) sered[w] = sed;
  __syncthreads();
  if (tid == 0) atomicAdd(&sumexp[b], sered[0] + sered[1] + sered[2] + sered[3]);
}

// ---------------- pass_b: per-batch threshold tau from histogram (parallel) ---------
__global__ void pass_b(const int* __restrict__ hist, float* __restrict__ tau,
                       const int* __restrict__ kptr) {
  __shared__ int hsh[NBIN];
  __shared__ int ps[256];
  int b = blockIdx.x, tid = threadIdx.x;
  int part = 0;
#pragma unroll
  for (int j = 0; j < 8; j++) {
    int v = hist[b * NBIN + tid * 8 + j];
    hsh[tid * 8 + j] = v;
    part += v;
  }
  ps[tid] = part;
  __syncthreads();
  if (tid == 0) {
    int k = kptr[0];
    if (k < 1) k = 1;
    if (k > KMAX) k = KMAX;
    long cum = 0;
    float tv = HFLOOR;
    for (int i = 255; i >= 0; i--) {
      if (cum + ps[i] >= k) {
        long r = k - cum;
        long c2 = 0;
        for (int j = 7; j >= 0; j--) {
          c2 += hsh[i * 8 + j];
          if (c2 >= r) { tv = HFLOOR + (i * 8 + j) * BW; break; }
        }
        break;
      }
      cum += ps[i];
    }
    tau[b] = tv;
  }
}

// ---------------- pass_c1_fast: compact hot cells into per-(b,bx)-tile lists --------
__global__ void pass_c1_fast(const float* __restrict__ cellmax, const float* __restrict__ tau,
                             int* __restrict__ tilecnt, int* __restrict__ tlist) {
  int i = blockIdx.x * blockDim.x + threadIdx.x;  // i == cid
  float v = cellmax[i];
  int b = i >> 16;
  if (v >= tau[b] - DELTA_C1) {
    int tile = (b << 6) | ((i >> 8) & 63);
    int pos = atomicAdd(&tilecnt[tile], 1);
    if (pos < TLCAP) tlist[tile * TLCAP + pos] = i;
  }
}

// ---------------- pass_c2_fast: tiled fp64 recompute of hot cells -------------------
// R5 rewrite. R2-R4 post-mortem: ANY per-thread register buffering of the W rows is
// defeated by the compiler — R2 sank the loads (serialized, ~13k cy/cell), R3/R4
// spilled them (WRITE_SIZE 157/158 MB scratch signature, VGPR 128/88). Fix: stage W
// through global_load_lds (ZERO VGPR, the pass_a mechanism). Per cell the wave needs
// 16 sw rows (8KB): 8 glds into a per-wave LDS pad (wave-uniform dest), then one
// per-wave s_waitcnt vmcnt(0) (no barrier — vmcnt is per-wave), dot reads W via
// ds_read_b128. Bank fix via PRE-SWIZZLED GLOBAL SRC (rule 21): lane at slot u
// fetches col-block u^(r&7); read back at slot j^(r&7) -> 8 bank groups, 2-way
// alias = free; nt groups broadcast. One ~400cy exposed window per ~2300cy cell,
// covered by the sibling wave (2 waves/SIMD). LDS 67.6K(Xt)+64K(Wpads)=131.6K.
// No launch_bounds min-waves arg (that knob caused the R2/R3 caps).
__global__ __launch_bounds__(512) void pass_c2_fast(
    const float* __restrict__ x, const float* __restrict__ sw,
    const float* __restrict__ sb, const float* __restrict__ tau,
    const int* __restrict__ tilecnt, const int* __restrict__ tlist,
    int* __restrict__ candcnt, double* __restrict__ candval, int* __restrict__ candidx) {
  __shared__ float Xt[128 * 132];  // 67584 B, t-major, col-XOR swizzled
  __shared__ float4 Wsh[8 * 512];  // 65536 B: per-wave 16 rows x 32 float4 (swizzled)
  int tile = blockIdx.x;
  int b = tile >> 6, bx = tile & 63;
  int cnt = tilecnt[tile];
  if (cnt <= 0) return;
  if (cnt > TLCAP) cnt = TLCAP;
  int tid = threadIdx.x;
  {
    // t-major staging (verified R4): thread loads (c, t4..t4+3) float4, 4 scalar writes.
    int cq = tid >> 5, tq = tid & 31, t4 = tq * 4;
    int sw4 = ((t4 >> 5) & 3) << 2;
    const float* xb = x + (size_t)b * CC * TT + bx * 128;
#pragma unroll
    for (int p = 0; p < 8; p++) {
      int c = p * 16 + cq;
      float4 v = *(const float4*)(xb + (size_t)c * TT + t4);
      int cc = c ^ sw4;
      Xt[(t4 + 0) * 132 + cc] = v.x;
      Xt[(t4 + 1) * 132 + cc] = v.y;
      Xt[(t4 + 2) * 132 + cc] = v.z;
      Xt[(t4 + 3) * 132 + cc] = v.w;
    }
  }
  __syncthreads();  // only barrier; waves may exit after this
  int wv = tid >> 6, lane = tid & 63;
  if (wv >= cnt) return;
  int nt = lane >> 4, r = lane & 15;
  int rs = r & 7;
  int rowp = lane >> 5, colp = lane & 31;  // staging lane geometry (2 rows x 32 f4)
  float tmb = tau[b] - DELTA_C2;
  int tbase = tile * TLCAP;
  float4* WbF4 = &Wsh[wv * 512];  // per-wave 8KB pad

  int s = wv;
  int cid = tlist[tbase + s];
  for (; s < cnt;) {
    int by_ = (cid >> 14) & 3, ta_ = cid & 255;
    int w_ = ta_ >> 6, lc_ = ta_ & 63, m_ = lc_ & 31, u_ = lc_ >> 5;
    int hbase = by_ * 128 + w_ * 32 + 4 * u_;
    int h = hbase + (r >> 2) * 8 + (r & 3);
    int t = bx * 128 + nt * 32 + m_;
    const float* xrp = &Xt[(nt * 32 + m_) * 132];
    // stage 16 W rows: call i covers rows {2i+rowp}; slot colp carries col-block
    // colp^(row&7) -> linear LDS placement realizes the XOR-swizzled layout.
#pragma unroll
    for (int i = 0; i < 8; i++) {
      int row_ = i * 2 + rowp;
      int h_ = hbase + ((row_ >> 2) << 3) + (row_ & 3);
      int c4 = colp ^ (row_ & 7);
      __builtin_amdgcn_global_load_lds(
          (glb_u32*)(sw + (size_t)h_ * CC + c4 * 4),
          (lds_u32*)((char*)WbF4 + i * 1024), 16, 0, 0);
    }
    float sbh = sb[h];
    int sn = s + 8;
    int cidN = (sn < cnt) ? tlist[tbase + sn] : 0;  // prefetched under same wait
    asm volatile("s_waitcnt vmcnt(0)" ::: "memory");
    __builtin_amdgcn_sched_barrier(0);
    double a0 = 0.0, a1 = 0.0, a2 = 0.0, a3 = 0.0;
#pragma unroll
    for (int j = 0; j < 32; j++) {
      float4 w4 = WbF4[r * 32 + (j ^ rs)];                       // cols 4j..4j+3
      float4 x4 = *(const float4*)(xrp + ((j * 4) ^ (nt * 4)));  // cols 4j..4j+3
      a0 = fma((double)x4.x, (double)w4.x, a0);
      a1 = fma((double)x4.y, (double)w4.y, a1);
      a2 = fma((double)x4.z, (double)w4.z, a2);
      a3 = fma((double)x4.w, (double)w4.w, a3);
    }
    double acc = a0 + a1 + a2 + a3 + (double)sbh;
    if (acc >= (double)tmb) {
      int pos = atomicAdd(&candcnt[b], 1);
      if (pos < CANDCAP) {
        candval[b * CANDCAP + pos] = acc;
        candidx[b * CANDCAP + pos] = h * TT + t;
      }
    }
    s = sn;
    cid = cidN;
  }
}

// ---------------- pass_d: exact top-k among candidates ------------------------------
__global__ void pass_d(const int* __restrict__ candcnt, const double* __restrict__ candval,
                       const int* __restrict__ candidx, const double* __restrict__ sumexp,
                       const int* __restrict__ kptr, int* __restrict__ selidx,
                       float* __restrict__ selval, int* __restrict__ selcnt) {
  __shared__ double sv[CANDCAP];
  __shared__ int si[CANDCAP];
  int b = blockIdx.x;
  int n = candcnt[b];
  if (n > CANDCAP) n = CANDCAP;
  int k = kptr[0];
  if (k < 0) k = 0;
  if (k > KMAX) k = KMAX;
  for (int i = threadIdx.x; i < n; i += blockDim.x) {
    sv[i] = candval[b * CANDCAP + i];
    si[i] = candidx[b * CANDCAP + i];
  }
  __syncthreads();
  double S = sumexp[b];
  for (int i = threadIdx.x; i < n; i += blockDim.x) {
    double vi = sv[i];
    int ii = si[i];
    int rank = 0;
    for (int q = 0; q < n; q++) {
      double vq = sv[q];
      rank += (vq > vi) || (vq == vi && si[q] < ii);
    }
    if (rank < k) {
      selidx[b * KMAX + rank] = ii;
      selval[b * KMAX + rank] = (float)(exp(vi) / S);
    }
  }
  if (threadIdx.x == 0) selcnt[b] = n < k ? n : k;
}

// ---------------- pass_e1: out = down_b broadcast -----------------------------------
__global__ void pass_e1(const float* __restrict__ db, float* __restrict__ out) {
  int row = blockIdx.x;  // b*C + c
  int c = row & (CC - 1);
  float v = db[c];
  float4 v4 = make_float4(v, v, v, v);
  float4* o = (float4*)(out + (size_t)row * TT);
#pragma unroll
  for (int q = 0; q < 8; q++) o[q * 256 + threadIdx.x] = v4;
}

// ---------------- pass_e2_fast: scatter using bf16 xf gather + dwt ------------------
// sig from bf16 x: err ~5e-4 abs; out err ~5e-4*val(5e-7)*dw(0.02) ~ 6e-12 << tol.
__global__ void pass_e2_fast(const short* __restrict__ xf, const float* __restrict__ uw,
                             const float* __restrict__ ub, const float* __restrict__ dwt,
                             const int* __restrict__ selidx, const float* __restrict__ selval,
                             const int* __restrict__ selcnt, float* __restrict__ out) {
  int b = blockIdx.y, j = blockIdx.x;
  if (j >= selcnt[b]) return;
  int idx = selidx[b * KMAX + j];
  float val = selval[b * KMAX + j];
  int h = idx >> 13, t = idx & (TT - 1);
  int bx = t >> 7, tl = t & 127, nt = tl >> 5, m = tl & 31;
  int lane = threadIdx.x;  // 64
  const short* xt = xf + ((size_t)b * 64 + bx) * 16384 + nt * 4096 + m * 8;
  int off = (lane >> 3) * 512 + ((lane >> 2) & 1) * 256 + (lane & 3) * 2;
  __hip_bfloat162 hv = *(const __hip_bfloat162*)(xt + off);
  float2 xv = __bfloat1622float2(hv);
  int c0 = lane * 2;
  float2 wv = *(const float2*)(uw + (size_t)h * CC + c0);
  float p = xv.x * wv.x + xv.y * wv.y;
#pragma unroll
  for (int mm = 1; mm < 64; mm <<= 1) p += __shfl_xor(p, mm);
  float sig = p + ub[h];
  float g = sig * val;
  float2 dv = *(const float2*)(dwt + (size_t)h * CC + c0);
  atomicAdd(&out[((size_t)b * CC + c0) * TT + t], g * dv.x);
  atomicAdd(&out[((size_t)b * CC + c0 + 1) * TT + t], g * dv.y);
}

// ================= slow-path (R3, proven) kernels for small ws ======================
__global__ __launch_bounds__(256) void pass_a_slow(const float* __restrict__ x,
                                                   const float* __restrict__ sw,
                                                   const float* __restrict__ sb,
                                                   float* __restrict__ cellmax,
                                                   int* __restrict__ hist,
                                                   double* __restrict__ sumexp) {
  __shared__ short Ws[128 * 128];
  __shared__ short Xs[128 * 128];
  __shared__ float sbs[128];
  int tid = threadIdx.x;
  int b = blockIdx.z, by = blockIdx.y, bx = blockIdx.x;
  int h0 = by * 128, t0g = bx * 128;
  const float* xb = x + (size_t)b * CC * TT;
  {
    int cq = tid >> 5, tq = tid & 31;
    int t0 = tq * 4;
#pragma unroll
    for (int p = 0; p < 4; p++) {
      int c0 = p * 32 + cq * 4;
      float r0[4], r1[4], r2[4], r3[4];
      *(float4*)r0 = *(const float4*)(xb + (size_t)(c0 + 0) * TT + t0g + t0);
      *(float4*)r1 = *(const float4*)(xb + (size_t)(c0 + 1) * TT + t0g + t0);
      *(float4*)r2 = *(const float4*)(xb + (size_t)(c0 + 2) * TT + t0g + t0);
      *(float4*)r3 = *(const float4*)(xb + (size_t)(c0 + 3) * TT + t0g + t0);
#pragma unroll
      for (int j = 0; j < 4; j++) {
        int t = t0 + j;
        int addr = t * 128 + ((((c0 >> 3) ^ (t & 15)) << 3) | (c0 & 7));
        union { __hip_bfloat162 h; unsigned int u; } a0, a1;
        a0.h = __float22bfloat162_rn(make_float2(r0[j], r1[j]));
        a1.h = __float22bfloat162_rn(make_float2(r2[j], r3[j]));
        *(uint2*)&Xs[addr] = make_uint2(a0.u, a1.u);
      }
    }
  }
  {
    int hh = tid >> 1, c4 = (tid & 1) << 2;
#pragma unroll
    for (int k = 0; k < 16; k++) {
      int c0 = k * 8 + c4;
      float r[4];
      *(float4*)r = *(const float4*)(sw + (size_t)(h0 + hh) * CC + c0);
      int addr = hh * 128 + ((((c0 >> 3) ^ (hh & 15)) << 3) | (c0 & 7));
      union { __hip_bfloat162 h; unsigned int u; } a0, a1;
      a0.h = __float22bfloat162_rn(make_float2(r[0], r[1]));
      a1.h = __float22bfloat162_rn(make_float2(r[2], r[3]));
      *(uint2*)&Ws[addr] = make_uint2(a0.u, a1.u);
    }
  }
  if (tid < 128) sbs[tid] = sb[h0 + tid];
  __syncthreads();
  int w = tid >> 6, lane = tid & 63, m = lane & 31, u = lane >> 5;
  f32x16 acc0, acc1, acc2, acc3;
#pragma unroll
  for (int r = 0; r < 16; r++) { acc0[r] = 0.f; acc1[r] = 0.f; acc2[r] = 0.f; acc3[r] = 0.f; }
  const short* wrow = &Ws[(w * 32 + m) * 128];
  const short* xrow = &Xs[m * 128];
#pragma unroll
  for (int kc = 0; kc < 8; kc++) {
    int pc = ((((kc << 1) | u) ^ (m & 15)) << 3);
    short8 af = *(const short8*)(wrow + pc);
    short8 b0 = *(const short8*)(xrow + 0 * 32 * 128 + pc);
    short8 b1 = *(const short8*)(xrow + 1 * 32 * 128 + pc);
    short8 b2 = *(const short8*)(xrow + 2 * 32 * 128 + pc);
    short8 b3 = *(const short8*)(xrow + 3 * 32 * 128 + pc);
    acc0 = __builtin_amdgcn_mfma_f32_32x32x16_bf16(af, b0, acc0, 0, 0, 0);
    acc1 = __builtin_amdgcn_mfma_f32_32x32x16_bf16(af, b1, acc1, 0, 0, 0);
    acc2 = __builtin_amdgcn_mfma_f32_32x32x16_bf16(af, b2, acc2, 0, 0, 0);
    acc3 = __builtin_amdgcn_mfma_f32_32x32x16_bf16(af, b3, acc3, 0, 0, 0);
  }
  float tmax = -1e30f;
  float se = 0.f;
#define EPI(ACC)                                                              \
  {                                                                           \
    _Pragma("unroll") for (int g = 0; g < 4; g++) {                           \
      float bias4[4];                                                         \
      *(float4*)bias4 = *(float4*)&sbs[w * 32 + g * 8 + u * 4];               \
      _Pragma("unroll") for (int q = 0; q < 4; q++) {                         \
        float s = ACC[g * 4 + q] + bias4[q];                                  \
        tmax = fmaxf(tmax, s);                                                \
        se += __expf(s);                                                      \
        if (s >= HFLOOR) {                                                    \
          int bin = (int)((s - HFLOOR) * INVBW);                              \
          if (bin > NBIN - 1) bin = NBIN - 1;                                 \
          atomicAdd(&hist[b * NBIN + bin], 1);                                \
        }                                                                     \
      }                                                                       \
    }                                                                         \
  }
  EPI(acc0) EPI(acc1) EPI(acc2) EPI(acc3)
#undef EPI
  int cid = ((b * 4 + by) * 64 + bx) * 256 + tid;
  cellmax[cid] = tmax;
  double sed = (double)se;
#pragma unroll
  for (int mm = 1; mm < 64; mm <<= 1) sed += __shfl_xor(sed, mm);
  if ((tid & 63) == 0) atomicAdd(&sumexp[b], sed);
}

__global__ void pass_c1_slow(const float* __restrict__ cellmax, const float* __restrict__ tau,
                             int* __restrict__ hotcnt, int* __restrict__ hotlist) {
  int i = blockIdx.x * blockDim.x + threadIdx.x;
  float v = cellmax[i];
  int b = i >> 16;
  if (v >= tau[b] - DELTA_C1) {
    int pos = atomicAdd(hotcnt, 1);
    if (pos < HOTCAP) hotlist[pos] = i;
  }
}

__global__ void pass_c2_slow(const float* __restrict__ x, const float* __restrict__ sw,
                             const float* __restrict__ sb, const float* __restrict__ tau,
                             const int* __restrict__ hotcnt, const int* __restrict__ hotlist,
                             int* __restrict__ candcnt, double* __restrict__ candval,
                             int* __restrict__ candidx) {
  int j = blockIdx.x;
  int n = hotcnt[0];
  if (n > HOTCAP) n = HOTCAP;
  if (j >= n) return;
  int cid = hotlist[j];
  int b = cid >> 16, by = (cid >> 14) & 3, bx = (cid >> 8) & 63;
  int ta = cid & 255;
  int w = ta >> 6, lane = ta & 63, m = lane & 31, u = lane >> 5;
  int e = threadIdx.x;
  int nt = e >> 4, r = e & 15;
  int h = by * 128 + w * 32 + (r >> 2) * 8 + (r & 3) + 4 * u;
  int t = bx * 128 + nt * 32 + m;
  const float* xb = x + (size_t)b * CC * TT;
  double acc = 0.0;
#pragma unroll 8
  for (int c = 0; c < CC; c++)
    acc += (double)xb[(size_t)c * TT + t] * (double)sw[h * CC + c];
  acc += (double)sb[h];
  float tm = tau[b] - DELTA_C2;
  if (acc >= (double)tm) {
    int pos = atomicAdd(&candcnt[b], 1);
    if (pos < CANDCAP) {
      candval[b * CANDCAP + pos] = acc;
      candidx[b * CANDCAP + pos] = h * TT + t;
    }
  }
}

__global__ void pass_e2_slow(const float* __restrict__ x, const float* __restrict__ uw,
                             const float* __restrict__ ub, const float* __restrict__ dw,
                             const int* __restrict__ selidx, const float* __restrict__ selval,
                             const int* __restrict__ selcnt, float* __restrict__ out) {
  int b = blockIdx.y, j = blockIdx.x;
  if (j >= selcnt[b]) return;
  int idx = selidx[b * KMAX + j];
  float val = selval[b * KMAX + j];
  int h = idx >> 13, t = idx & (TT - 1);
  int c = threadIdx.x;
  const float* xb = x + (size_t)b * CC * TT;
  float p = xb[(size_t)c * TT + t] * uw[h * CC + c] +
            xb[(size_t)(c + 64) * TT + t] * uw[h * CC + c + 64];
#pragma unroll
  for (int m = 1; m < 64; m <<= 1) p += __shfl_xor(p, m);
  float sig = p + ub[h];
  float g = sig * val;
  atomicAdd(&out[((size_t)b * CC + c) * TT + t], g * dw[c * HH + h]);
  atomicAdd(&out[((size_t)b * CC + c + 64) * TT + t], g * dw[(c + 64) * HH + h]);
}

extern "C" void kernel_launch(void* const* d_in, const int* in_sizes, int n_in,
                              void* d_out, int out_size, void* d_ws, size_t ws_size,
                              hipStream_t stream) {
  const float* x = (const float*)d_in[0];
  const float* uw = (const float*)d_in[1];
  const float* ub = (const float*)d_in[2];
  const float* sw = (const float*)d_in[3];
  const float* sb = (const float*)d_in[4];
  const float* dw = (const float*)d_in[5];
  const float* db = (const float*)d_in[6];
  const int* kptr = (const int*)d_in[7];
  float* out = (float*)d_out;
  char* ws = (char*)d_ws;

  if (ws_size >= (size_t)N_NEED) {
    int* hist = (int*)(ws + N_HIST);
    double* sumexp = (double*)(ws + N_SUMEXP);
    int* candcnt = (int*)(ws + N_CANDCNT);
    int* tilecnt = (int*)(ws + N_TILECNT);
    float* tau = (float*)(ws + N_TAU);
    int* selcnt = (int*)(ws + N_SELCNT);
    float* cellmax = (float*)(ws + N_CELLMAX);
    int* tlist = (int*)(ws + N_TLIST);
    double* candval = (double*)(ws + N_CANDVAL);
    int* candidx = (int*)(ws + N_CANDIDX);
    int* selidx = (int*)(ws + N_SELIDX);
    float* selval = (float*)(ws + N_SELVAL);
    short* swb = (short*)(ws + N_SWB);
    short* xf = (short*)(ws + N_XF);
    float* dwt = (float*)(ws + N_DWT);

    (void)hipMemsetAsync(d_ws, 0, N_ZERO, stream);
    prep_w<<<32, 256, 0, stream>>>(sw, swb);
    prep_dwt<<<256, 256, 0, stream>>>(dw, dwt);
    prep_xt<<<dim3(64, 32), 256, 0, stream>>>(x, xf);
    pass_a_lds<<<dim3(256, 32), 256, 0, stream>>>(xf, swb, sb, cellmax, hist, sumexp);
    pass_b<<<32, 256, 0, stream>>>(hist, tau, kptr);
    pass_c1_fast<<<8192, 256, 0, stream>>>(cellmax, tau, tilecnt, tlist);
    pass_c2_fast<<<TILES, 512, 0, stream>>>(x, sw, sb, tau, tilecnt, tlist, candcnt,
                                            candval, candidx);
    pass_d<<<32, 256, 0, stream>>>(candcnt, candval, candidx, sumexp, kptr, selidx,
                                   selval, selcnt);
    pass_e1<<<BB * CC, 256, 0, stream>>>(db, out);
    pass_e2_fast<<<dim3(KMAX, BB), 64, 0, stream>>>(xf, uw, ub, dwt, selidx, selval,
                                                    selcnt, out);
  } else {
    int* hist = (int*)(ws + O_HIST);
    double* sumexp = (double*)(ws + O_SUMEXP);
    int* candcnt = (int*)(ws + O_CANDCNT);
    int* hotcnt = (int*)(ws + O_HOTCNT);
    float* tau = (float*)(ws + O_TAU);
    int* selcnt = (int*)(ws + O_SELCNT);
    float* cellmax = (float*)(ws + O_CELLMAX);
    int* hotlist = (int*)(ws + O_HOTLIST);
    double* candval = (double*)(ws + O_CANDVAL);
    int* candidx = (int*)(ws + O_CANDIDX);
    int* selidx = (int*)(ws + O_SELIDX);
    float* selval = (float*)(ws + O_SELVAL);

    (void)hipMemsetAsync(d_ws, 0, O_ZERO, stream);
    pass_a_slow<<<dim3(64, 4, 32), 256, 0, stream>>>(x, sw, sb, cellmax, hist, sumexp);
    pass_b<<<32, 256, 0, stream>>>(hist, tau, kptr);
    pass_c1_slow<<<8192, 256, 0, stream>>>(cellmax, tau, hotcnt, hotlist);
    pass_c2_slow<<<HOTCAP, 64, 0, stream>>>(x, sw, sb, tau, hotcnt, hotlist, candcnt,
                                            candval, candidx);
    pass_d<<<32, 256, 0, stream>>>(candcnt, candval, candidx, sumexp, kptr, selidx,
                                   selval, selcnt);
    pass_e1<<<BB * CC, 256, 0, stream>>>(db, out);
    pass_e2_slow<<<dim3(KMAX, BB), 64, 0, stream>>>(x, uw, ub, dw, selidx, selval,
                                                    selcnt, out);
  }
}